// Round 17
// baseline (22179.762 us; speedup 1.0000x reference)
//
#include <hip/hip_runtime.h>
#include <cmath>

#define TT 512
#define BB 32
#define HH 1024
#define G3 3072

// ---------------------------------------------------------------------------
// mv_phase (fallback k_scan only): LDS-staged matvec, round-6 structure.
// ---------------------------------------------------------------------------
__device__ __forceinline__ void mv_phase(
    float (*wAll)[HH],              // rows [wrow, wrow+12)
    float* stgL,                    // [32*256]
    float (*part)[12][32],          // [16][12][32]
    const float* __restrict__ src,  // [32][1024] row-major
    int wrow, int tid)
{
    const int wv = tid >> 6, l = tid & 63;
    const int ks = l >> 3, bg = l & 7;
    float acc[12][4];
#pragma unroll
    for (int r = 0; r < 12; r++) {
        acc[r][0] = 0.f; acc[r][1] = 0.f; acc[r][2] = 0.f; acc[r][3] = 0.f;
    }

    float4 ld[4];
#pragma unroll
    for (int i = 0; i < 4; i++)
        ld[i] = *(const float4*)&src[(size_t)(i * 8 + wv) * HH + l * 4];

#pragma unroll
    for (int c = 0; c < 4; c++) {
        __syncthreads();
#pragma unroll
        for (int i = 0; i < 4; i++) {
            int b = i * 8 + wv;
            *(float4*)&stgL[b * 256 + ((l ^ ((b >> 2) & 7)) << 2)] = ld[i];
        }
        __syncthreads();
        if (c < 3) {
#pragma unroll
            for (int i = 0; i < 4; i++)
                ld[i] = *(const float4*)&src[(size_t)(i * 8 + wv) * HH + (c + 1) * 256 + l * 4];
        }
        const int kw = c * 256 + wv * 32 + ks * 4;
        const int kb = wv * 8 + ks;
        float4 h4[4];
#pragma unroll
        for (int e = 0; e < 4; e++) {
            int b = bg * 4 + e;
            h4[e] = *(const float4*)&stgL[b * 256 + ((kb ^ ((b >> 2) & 7)) << 2)];
        }
#pragma unroll
        for (int r = 0; r < 12; r++) {
            float4 w4 = *(const float4*)&wAll[wrow + r][kw];
#pragma unroll
            for (int e = 0; e < 4; e++) {
                acc[r][e] = fmaf(w4.x, h4[e].x, acc[r][e]);
                acc[r][e] = fmaf(w4.y, h4[e].y, acc[r][e]);
                acc[r][e] = fmaf(w4.z, h4[e].z, acc[r][e]);
                acc[r][e] = fmaf(w4.w, h4[e].w, acc[r][e]);
            }
        }
    }
#pragma unroll
    for (int r = 0; r < 12; r++)
#pragma unroll
        for (int e = 0; e < 4; e++) {
            float v = acc[r][e];
            v += __shfl_xor(v, 16, 64);
            v += __shfl_xor(v, 32, 64);
            acc[r][e] = v;
        }
    if (l < 16) {
        int s = l >> 3, bgw = l & 7;
#pragma unroll
        for (int r = 0; r < 12; r++) {
            float4 o = make_float4(acc[r][0], acc[r][1], acc[r][2], acc[r][3]);
            *(float4*)&part[wv * 2 + s][r][bgw * 4] = o;
        }
    }
}

// ---------------------------------------------------------------------------
// Fallback-only scan (ws too small for chunked path). Unchanged.
// ---------------------------------------------------------------------------
template<int IN_DIM>
__global__ __launch_bounds__(512, 2) void k_scan(
    const float* __restrict__ xsrc,
    const float* __restrict__ Wih,
    const float* __restrict__ Whh,
    const float* __restrict__ bih,
    const float* __restrict__ bhh,
    float* __restrict__ y,
    int* __restrict__ barx,
    float* __restrict__ pool)
{
    __shared__ float wAll[24][HH];
    __shared__ float stgL[32 * 256];
    __shared__ float part[16][12][32];
    __shared__ float bi[12], bh[12];
    __shared__ double pool_l[128];

    const int tid = threadIdx.x;
    const int j0 = blockIdx.x * 4;

    for (int i = tid; i < 12 * 256; i += 512) {
        int r = i >> 8, c4 = (i & 255) * 4;
        int g = r >> 2, jj = r & 3;
        *(float4*)&wAll[r][c4] =
            *(const float4*)&Whh[(size_t)(g * HH + j0 + jj) * HH + c4];
    }
    if (IN_DIM == HH) {
        for (int i = tid; i < 12 * 256; i += 512) {
            int r = i >> 8, c4 = (i & 255) * 4;
            int g = r >> 2, jj = r & 3;
            *(float4*)&wAll[12 + r][c4] =
                *(const float4*)&Wih[(size_t)(g * HH + j0 + jj) * HH + c4];
        }
    } else {
        if (tid < 96) {
            int r = tid >> 3, d = tid & 7;
            int g = r >> 2, jj = r & 3;
            wAll[12 + r][d] = Wih[(size_t)(g * HH + j0 + jj) * IN_DIM + d];
        }
    }
    if (tid < 12) {
        int g = tid >> 2, jj = tid & 3;
        bi[tid] = bih[g * HH + j0 + jj];
        bh[tid] = bhh[g * HH + j0 + jj];
    }
    if (tid < 128) pool_l[tid] = 0.0;
    __syncthreads();

    float hp_reg = 0.f;
    for (int t = 0; t < TT; t++) {
        double ig0 = 0.0, ig1 = 0.0, ig2 = 0.0;
        if (IN_DIM == HH) {
            mv_phase(wAll, stgL, part, xsrc + (size_t)t * BB * HH, 12, tid);
            __syncthreads();
            if (tid < 128) {
                int b = tid >> 2, jj = tid & 3;
                ig0 = bi[jj]; ig1 = bi[4 + jj]; ig2 = bi[8 + jj];
#pragma unroll
                for (int p = 0; p < 16; p++) {
                    ig0 += part[p][jj][b];
                    ig1 += part[p][4 + jj][b];
                    ig2 += part[p][8 + jj][b];
                }
            }
        }
        if (t > 0) {
            if (tid < 8) {
                const int target = 32 * t;
                while (__hip_atomic_load(&barx[tid * 16], __ATOMIC_RELAXED,
                                         __HIP_MEMORY_SCOPE_AGENT) < target)
                    __builtin_amdgcn_s_sleep(1);
            }
            __syncthreads();
            mv_phase(wAll, stgL, part, y + (size_t)(t - 1) * BB * HH, 0, tid);
            __syncthreads();
        }
        if (tid < 128) {
            int b = tid >> 2, jj = tid & 3, jg = j0 + jj;
            double hg0 = bh[jj], hg1 = bh[4 + jj], hg2 = bh[8 + jj];
            if (t > 0) {
#pragma unroll
                for (int p = 0; p < 16; p++) {
                    hg0 += part[p][jj][b];
                    hg1 += part[p][4 + jj][b];
                    hg2 += part[p][8 + jj][b];
                }
            }
            if (IN_DIM != HH) {
                const float* xp = xsrc + ((size_t)b * TT + t) * IN_DIM;
                float xv[8];
                *(float4*)&xv[0] = *(const float4*)&xp[0];
                *(float4*)&xv[4] = *(const float4*)&xp[4];
                float s0 = 0.f, s1 = 0.f, s2 = 0.f;
#pragma unroll
                for (int d = 0; d < 8; d++) {
                    s0 = fmaf(wAll[12 + jj][d], xv[d], s0);
                    s1 = fmaf(wAll[16 + jj][d], xv[d], s1);
                    s2 = fmaf(wAll[20 + jj][d], xv[d], s2);
                }
                ig0 = (double)bi[jj] + s0;
                ig1 = (double)bi[4 + jj] + s1;
                ig2 = (double)bi[8 + jj] + s2;
            }
            float rr = 1.f / (1.f + expf(-(float)(ig0 + hg0)));
            float zz = 1.f / (1.f + expf(-(float)(ig1 + hg1)));
            float nn = tanhf((float)(ig2 + (double)rr * hg2));
            float hnew = (1.f - zz) * nn + zz * hp_reg;
            hp_reg = hnew;
            __hip_atomic_store(&y[(size_t)t * BB * HH + b * HH + jg], hnew,
                               __ATOMIC_RELAXED, __HIP_MEMORY_SCOPE_AGENT);
            if (pool != nullptr) pool_l[tid] += (double)hnew;
        }
        if (t < TT - 1) {
            __syncthreads();
            if (tid == 0)
                __hip_atomic_fetch_add(&barx[(blockIdx.x & 7) * 16], 1,
                                       __ATOMIC_RELAXED, __HIP_MEMORY_SCOPE_AGENT);
        }
    }
    __syncthreads();
    if (pool != nullptr && tid < 128) {
        int b = tid >> 2, jj = tid & 3;
        pool[b * HH + j0 + jj] = (float)(pool_l[tid] * (1.0 / 512.0));
    }
}

// ---------------------------------------------------------------------------
// Hidden-only CHUNKED scan, r17: 1024 threads (16 waves) per block.
// r16's direct-load structure kept; per-lane k-tile halves (2 chunks of
// c*512+wv*32+ks*4). Reduce gains a shfl_xor(8) round: lane=ks*8+bg, xor
// 8/16/32 folds all 8 ks -> lanes l<8 hold bg's full slice; part stays
// [16][12][32] (p=wv), gate sum unchanged. 2x waves/SIMD halves the VALU
// wall and hides h-load/poll latency. launch_bounds(1024,4) caps VGPR<=128
// (16 waves/CU resident).
// ---------------------------------------------------------------------------
__global__ __launch_bounds__(1024, 4) void k_scan_x(
    const float* __restrict__ xg,
    const float* __restrict__ Whh,
    const float* __restrict__ bhh,
    float* __restrict__ y,
    int* __restrict__ flagx,          // [256] per-block step flags (zeroed)
    double* __restrict__ pool,
    int t0, int t1)
{
    __shared__ float wAll[12][HH];        // 48 KB
    __shared__ float part[16][12][32];    // 24.6 KB
    __shared__ float bh[12];
    __shared__ double pool_l[128];

    const int tid = threadIdx.x;
    const int j0 = blockIdx.x * 4;
    const int wv = tid >> 6, l = tid & 63;
    const int ks = l >> 3, bg = l & 7;

    for (int i = tid; i < 12 * 256; i += 1024) {
        int r = i >> 8, c4 = (i & 255) * 4;
        int g = r >> 2, jj = r & 3;
        *(float4*)&wAll[r][c4] =
            *(const float4*)&Whh[(size_t)(g * HH + j0 + jj) * HH + c4];
    }
    if (tid < 12) bh[tid] = bhh[(tid >> 2) * HH + j0 + (tid & 3)];
    if (tid < 128) pool_l[tid] = 0.0;

    const int gb = tid >> 2, gjj = tid & 3;
    float hp_reg = 0.f;
    if (t0 > 0 && tid < 128)
        hp_reg = y[(size_t)(t0 - 1) * BB * HH + gb * HH + j0 + gjj];
    __syncthreads();

    for (int t = t0; t < t1; t++) {
        // prefetch this step's input gates before the barrier poll
        float xr = 0.f, xz = 0.f, xn = 0.f;
        if (tid < 128) {
            const float* xrow = xg + ((size_t)(t - t0) * BB + gb) * G3;
            xr = xrow[j0 + gjj];
            xz = xrow[HH + j0 + gjj];
            xn = xrow[2 * HH + j0 + gjj];
        }
        if (t > t0) {
            if (tid < 64) {                      // wave 0 polls all 256 flags
                const int target = t - t0;
                const int* fp = flagx + tid * 4;
                for (;;) {
                    int f0 = __hip_atomic_load(fp + 0, __ATOMIC_RELAXED,
                                               __HIP_MEMORY_SCOPE_AGENT);
                    int f1 = __hip_atomic_load(fp + 1, __ATOMIC_RELAXED,
                                               __HIP_MEMORY_SCOPE_AGENT);
                    int f2 = __hip_atomic_load(fp + 2, __ATOMIC_RELAXED,
                                               __HIP_MEMORY_SCOPE_AGENT);
                    int f3 = __hip_atomic_load(fp + 3, __ATOMIC_RELAXED,
                                               __HIP_MEMORY_SCOPE_AGENT);
                    int m01 = f0 < f1 ? f0 : f1;
                    int m23 = f2 < f3 ? f2 : f3;
                    int m = m01 < m23 ? m01 : m23;
                    if (__all(m >= target)) break;
                    __builtin_amdgcn_s_sleep(1);
                }
            }
            __syncthreads();
        }
        if (t > 0) {
            const float* hsrc = y + (size_t)(t - 1) * BB * HH;
            // 8 direct loads, all in flight at once
            float4 hr[2][4];
#pragma unroll
            for (int c = 0; c < 2; c++)
#pragma unroll
                for (int e = 0; e < 4; e++)
                    hr[c][e] = *(const float4*)
                        &hsrc[(size_t)(bg * 4 + e) * HH + c * 512 + wv * 32 + ks * 4];

            float acc[12][4];
#pragma unroll
            for (int r = 0; r < 12; r++) {
                acc[r][0] = 0.f; acc[r][1] = 0.f; acc[r][2] = 0.f; acc[r][3] = 0.f;
            }
#pragma unroll
            for (int c = 0; c < 2; c++) {
                const int kw = c * 512 + wv * 32 + ks * 4;
#pragma unroll
                for (int r = 0; r < 12; r++) {
                    float4 w4 = *(const float4*)&wAll[r][kw];
#pragma unroll
                    for (int e = 0; e < 4; e++) {
                        acc[r][e] = fmaf(w4.x, hr[c][e].x, acc[r][e]);
                        acc[r][e] = fmaf(w4.y, hr[c][e].y, acc[r][e]);
                        acc[r][e] = fmaf(w4.z, hr[c][e].z, acc[r][e]);
                        acc[r][e] = fmaf(w4.w, hr[c][e].w, acc[r][e]);
                    }
                }
            }
#pragma unroll
            for (int r = 0; r < 12; r++)
#pragma unroll
                for (int e = 0; e < 4; e++) {
                    float v = acc[r][e];
                    v += __shfl_xor(v, 8, 64);
                    v += __shfl_xor(v, 16, 64);
                    v += __shfl_xor(v, 32, 64);
                    acc[r][e] = v;
                }
            if (l < 8) {   // ks==0 lanes: bg = l, full k-slice sum of wave wv
#pragma unroll
                for (int r = 0; r < 12; r++) {
                    float4 o = make_float4(acc[r][0], acc[r][1], acc[r][2], acc[r][3]);
                    *(float4*)&part[wv][r][l * 4] = o;
                }
            }
            __syncthreads();
        }
        if (tid < 128) {
            double hg0 = bh[gjj], hg1 = bh[4 + gjj], hg2 = bh[8 + gjj];
            if (t > 0) {
#pragma unroll
                for (int p = 0; p < 16; p++) {
                    hg0 += part[p][gjj][gb];
                    hg1 += part[p][4 + gjj][gb];
                    hg2 += part[p][8 + gjj][gb];
                }
            }
            float rr = 1.f / (1.f + expf(-(xr + (float)hg0)));
            float zz = 1.f / (1.f + expf(-(xz + (float)hg1)));
            float nn = tanhf(xn + rr * (float)hg2);
            float hnew = (1.f - zz) * nn + zz * hp_reg;
            hp_reg = hnew;
            __hip_atomic_store(&y[(size_t)t * BB * HH + gb * HH + j0 + gjj], hnew,
                               __ATOMIC_RELAXED, __HIP_MEMORY_SCOPE_AGENT);
            if (pool != nullptr) pool_l[tid] += (double)hnew;
        }
        if (t < t1 - 1) {
            __syncthreads();   // acks all waves' y[t] stores (vmcnt0 drain)
            if (tid == 0)
                __hip_atomic_store(&flagx[blockIdx.x], t - t0 + 1,
                                   __ATOMIC_RELAXED, __HIP_MEMORY_SCOPE_AGENT);
        }
    }
    __syncthreads();
    if (pool != nullptr && tid < 128)
        pool[gb * HH + j0 + gjj] += pool_l[tid];   // serialized chunk kernels
}

// ---------------------------------------------------------------------------
// pooled_f[i] = pooled_d[i] / 512
// ---------------------------------------------------------------------------
__global__ __launch_bounds__(512) void k_poolfin(const double* __restrict__ pd,
                                                 float* __restrict__ pf)
{
    int i = blockIdx.x * 512 + threadIdx.x;
    if (i < BB * HH) pf[i] = (float)(pd[i] * (1.0 / 512.0));
}

// ---------------------------------------------------------------------------
// xg GEMM (layers 1,2): C[m][n] = sum_k A[m][k]*Bw[n][k] + bias[n]
// 128x128 tile, BK=16, 256 threads, 8x8 microtile.
// ---------------------------------------------------------------------------
__global__ __launch_bounds__(256, 2) void k_gemm_xg(const float* __restrict__ A,
                                                    const float* __restrict__ Bw,
                                                    const float* __restrict__ bias,
                                                    float* __restrict__ C)
{
    __shared__ float As[16][132];
    __shared__ float Bs[16][132];
    const int tid = threadIdx.x;
    const int tx = tid & 15, ty = tid >> 4;
    const int bm = blockIdx.x * 128, bn = blockIdx.y * 128;
    float acc[8][8];
#pragma unroll
    for (int i = 0; i < 8; i++)
#pragma unroll
        for (int j = 0; j < 8; j++) acc[i][j] = 0.f;

    const int srow = tid >> 1, sch = (tid & 1) * 8;
    for (int k0 = 0; k0 < HH; k0 += 16) {
        {
            const float* ap = &A[(size_t)(bm + srow) * HH + k0 + sch];
            float4 v0 = *(const float4*)ap;
            float4 v1 = *(const float4*)(ap + 4);
            As[sch + 0][srow] = v0.x; As[sch + 1][srow] = v0.y;
            As[sch + 2][srow] = v0.z; As[sch + 3][srow] = v0.w;
            As[sch + 4][srow] = v1.x; As[sch + 5][srow] = v1.y;
            As[sch + 6][srow] = v1.z; As[sch + 7][srow] = v1.w;
            const float* bp = &Bw[(size_t)(bn + srow) * HH + k0 + sch];
            float4 u0 = *(const float4*)bp;
            float4 u1 = *(const float4*)(bp + 4);
            Bs[sch + 0][srow] = u0.x; Bs[sch + 1][srow] = u0.y;
            Bs[sch + 2][srow] = u0.z; Bs[sch + 3][srow] = u0.w;
            Bs[sch + 4][srow] = u1.x; Bs[sch + 5][srow] = u1.y;
            Bs[sch + 6][srow] = u1.z; Bs[sch + 7][srow] = u1.w;
        }
        __syncthreads();
#pragma unroll
        for (int k = 0; k < 16; k++) {
            float a[8], b[8];
            *(float4*)&a[0] = *(const float4*)&As[k][ty * 8];
            *(float4*)&a[4] = *(const float4*)&As[k][ty * 8 + 4];
            *(float4*)&b[0] = *(const float4*)&Bs[k][tx * 8];
            *(float4*)&b[4] = *(const float4*)&Bs[k][tx * 8 + 4];
#pragma unroll
            for (int i = 0; i < 8; i++)
#pragma unroll
                for (int j = 0; j < 8; j++)
                    acc[i][j] = fmaf(a[i], b[j], acc[i][j]);
        }
        __syncthreads();
    }
#pragma unroll
    for (int i = 0; i < 8; i++) {
        float o[8];
#pragma unroll
        for (int j = 0; j < 8; j++) o[j] = acc[i][j] + bias[bn + tx * 8 + j];
        float* cp = &C[(size_t)(bm + ty * 8 + i) * G3 + bn + tx * 8];
        *(float4*)cp = *(float4*)&o[0];
        *(float4*)(cp + 4) = *(float4*)&o[4];
    }
}

// ---------------------------------------------------------------------------
// xg GEMM for layer 0 (K=8): C[m][n] = sum_{k<8} x[b][t][k]*W[n][k] + bias[n]
// m local to chunk: m = (t-t0)*32 + b. Grid (CH*32/128, 24), 256 threads.
// ---------------------------------------------------------------------------
__global__ __launch_bounds__(256) void k_gemm_xg0(const float* __restrict__ x,
                                                  const float* __restrict__ W,
                                                  const float* __restrict__ bias,
                                                  float* __restrict__ C,
                                                  int t0)
{
    __shared__ float As[128][8];
    __shared__ float Bs[128][8];
    const int tid = threadIdx.x;
    const int bm = blockIdx.x * 128, bn = blockIdx.y * 128;
    {
        int r = tid >> 1, hf = (tid & 1) * 4;
        int m = bm + r;                       // chunk-local row
        int b = m & 31, tt = t0 + (m >> 5);
        *(float4*)&As[r][hf] = *(const float4*)&x[((size_t)b * TT + tt) * 8 + hf];
        *(float4*)&Bs[r][hf] = *(const float4*)&W[(size_t)(bn + r) * 8 + hf];
    }
    __syncthreads();
    const int tx = tid & 15, ty = tid >> 4;
    float acc[8][8];
#pragma unroll
    for (int i = 0; i < 8; i++)
#pragma unroll
        for (int j = 0; j < 8; j++) acc[i][j] = 0.f;
#pragma unroll
    for (int k = 0; k < 8; k++) {
        float a[8], b[8];
#pragma unroll
        for (int i = 0; i < 8; i++) a[i] = As[ty * 8 + i][k];
#pragma unroll
        for (int j = 0; j < 8; j++) b[j] = Bs[tx * 8 + j][k];
#pragma unroll
        for (int i = 0; i < 8; i++)
#pragma unroll
            for (int j = 0; j < 8; j++)
                acc[i][j] = fmaf(a[i], b[j], acc[i][j]);
    }
#pragma unroll
    for (int i = 0; i < 8; i++) {
        float o[8];
#pragma unroll
        for (int j = 0; j < 8; j++) o[j] = acc[i][j] + bias[bn + tx * 8 + j];
        float* cp = &C[(size_t)(bm + ty * 8 + i) * G3 + bn + tx * 8];
        *(float4*)cp = *(float4*)&o[0];
        *(float4*)(cp + 4) = *(float4*)&o[4];
    }
}

// ---------------------------------------------------------------------------
__global__ __launch_bounds__(256) void k_fc(const float* __restrict__ in,
                                            const float* __restrict__ w,
                                            const float* __restrict__ bias,
                                            float* __restrict__ out,
                                            int ind, int outd, int dorelu)
{
    int b = blockIdx.y;
    int o = blockIdx.x * 256 + threadIdx.x;
    if (o >= outd) return;
    const float* ip = in + (size_t)b * ind;
    const float* wp = w + (size_t)o * ind;
    double s = (double)bias[o];
    for (int k = 0; k < ind; k += 4) {
        float4 wv = *(const float4*)&wp[k];
        float4 iv = *(const float4*)&ip[k];
        s += (double)iv.x * wv.x + (double)iv.y * wv.y
           + (double)iv.z * wv.z + (double)iv.w * wv.w;
    }
    float v = (float)s;
    if (dorelu) v = fmaxf(v, 0.f);
    out[(size_t)b * outd + o] = v;
}

// ---------------------------------------------------------------------------
extern "C" void kernel_launch(void* const* d_in, const int* in_sizes, int n_in,
                              void* d_out, int out_size, void* d_ws, size_t ws_size,
                              hipStream_t stream)
{
    (void)in_sizes; (void)n_in; (void)out_size;
    const float* x    = (const float*)d_in[0];
    const float* Wih[3] = {(const float*)d_in[1], (const float*)d_in[5], (const float*)d_in[9]};
    const float* Whh[3] = {(const float*)d_in[2], (const float*)d_in[6], (const float*)d_in[10]};
    const float* bih[3] = {(const float*)d_in[3], (const float*)d_in[7], (const float*)d_in[11]};
    const float* bhh[3] = {(const float*)d_in[4], (const float*)d_in[8], (const float*)d_in[12]};
    const float* fc1w = (const float*)d_in[13];
    const float* fc1b = (const float*)d_in[14];
    const float* fc2w = (const float*)d_in[15];
    const float* fc2b = (const float*)d_in[16];
    const float* fc3w = (const float*)d_in[17];
    const float* fc3b = (const float*)d_in[18];

    // workspace layout
    int*    bars     = (int*)d_ws;                 // 96 x 128 ints (fallback)
    int*    flags    = bars + 96 * 128;            // 96 x 256 ints (scan_x)
    double* pooled_d = (double*)(flags + 96 * 256);   // 256 KB
    float*  pooled_f = (float*)(pooled_d + BB * HH);  // 128 KB
    float*  fc1o     = pooled_f + BB * HH;
    float*  fc2o     = fc1o + BB * 512;
    float*  y0       = fc2o + BB * 256;               // 67.1 MB
    float*  y1       = y0 + (size_t)TT * BB * HH;     // 67.1 MB
    float*  xg       = y1 + (size_t)TT * BB * HH;     // CH*393 KB

    const size_t base = (size_t)((char*)xg - (char*)d_ws);
    if (ws_size < base) return;

    int CH = 0;
    for (int c = 512; c >= 16; c >>= 1) {
        if (base + (size_t)c * BB * G3 * 4 <= ws_size) { CH = c; break; }
    }

    hipMemsetAsync(bars, 0, (96 * 128 + 96 * 256) * sizeof(int), stream);
    hipMemsetAsync(pooled_d, 0, BB * HH * sizeof(double), stream);

    int binst = 0;
    if (CH > 0) {
        // layer 0: K=8 gemm + hidden-only scan (same structure as layers 1,2)
        for (int t0 = 0; t0 < TT; t0 += CH) {
            k_gemm_xg0<<<dim3(CH * BB / 128, G3 / 128), 256, 0, stream>>>(
                x, Wih[0], bih[0], xg, t0);
            k_scan_x<<<256, 1024, 0, stream>>>(
                xg, Whh[0], bhh[0], y0, flags + (binst++) * 256, nullptr, t0, t0 + CH);
        }
        float* ybuf[2] = {y0, y1};
        for (int l = 1; l <= 2; l++) {
            const float* src = ybuf[(l - 1) & 1];
            float* dst = ybuf[l & 1];   // layer 2 reuses y0
            double* pl = (l == 2) ? pooled_d : nullptr;
            for (int t0 = 0; t0 < TT; t0 += CH) {
                k_gemm_xg<<<dim3(CH * BB / 128, G3 / 128), 256, 0, stream>>>(
                    src + (size_t)t0 * BB * HH, Wih[l], bih[l], xg);
                k_scan_x<<<256, 1024, 0, stream>>>(
                    xg, Whh[l], bhh[l], dst, flags + (binst++) * 256, pl, t0, t0 + CH);
            }
        }
        k_poolfin<<<(BB * HH + 511) / 512, 512, 0, stream>>>(pooled_d, pooled_f);
        k_fc<<<dim3(2, 32), 256, 0, stream>>>(pooled_f, fc1w, fc1b, fc1o, HH, 512, 1);
    } else {
        // fallback (never expected: ws >= 235 MB proven in round 10)
        float* pooled_fb = pooled_f;
        k_scan<8><<<256, 512, 0, stream>>>(x, Wih[0], Whh[0], bih[0], bhh[0], y0,
                                           bars + (binst++) * 128, nullptr);
        k_scan<HH><<<256, 512, 0, stream>>>(y0, Wih[1], Whh[1], bih[1], bhh[1], y1,
                                            bars + (binst++) * 128, nullptr);
        k_scan<HH><<<256, 512, 0, stream>>>(y1, Wih[2], Whh[2], bih[2], bhh[2], y0,
                                            bars + (binst++) * 128, pooled_fb);
        k_fc<<<dim3(2, 32), 256, 0, stream>>>(pooled_fb, fc1w, fc1b, fc1o, HH, 512, 1);
    }

    k_fc<<<dim3(1, 32), 256, 0, stream>>>(fc1o, fc2w, fc2b, fc2o, 512, 256, 1);
    k_fc<<<dim3(1, 32), 256, 0, stream>>>(fc2o, fc3w, fc3b, (float*)d_out, 256, 1, 0);
}

// Round 18
// 18527.052 us; speedup vs baseline: 1.1972x; 1.1972x over previous
//
#include <hip/hip_runtime.h>
#include <cmath>

#define TT 512
#define BB 32
#define HH 1024
#define G3 3072

// ---------------------------------------------------------------------------
// mv_phase (fallback k_scan only): LDS-staged matvec, round-6 structure.
// ---------------------------------------------------------------------------
__device__ __forceinline__ void mv_phase(
    float (*wAll)[HH],              // rows [wrow, wrow+12)
    float* stgL,                    // [32*256]
    float (*part)[12][32],          // [16][12][32]
    const float* __restrict__ src,  // [32][1024] row-major
    int wrow, int tid)
{
    const int wv = tid >> 6, l = tid & 63;
    const int ks = l >> 3, bg = l & 7;
    float acc[12][4];
#pragma unroll
    for (int r = 0; r < 12; r++) {
        acc[r][0] = 0.f; acc[r][1] = 0.f; acc[r][2] = 0.f; acc[r][3] = 0.f;
    }

    float4 ld[4];
#pragma unroll
    for (int i = 0; i < 4; i++)
        ld[i] = *(const float4*)&src[(size_t)(i * 8 + wv) * HH + l * 4];

#pragma unroll
    for (int c = 0; c < 4; c++) {
        __syncthreads();
#pragma unroll
        for (int i = 0; i < 4; i++) {
            int b = i * 8 + wv;
            *(float4*)&stgL[b * 256 + ((l ^ ((b >> 2) & 7)) << 2)] = ld[i];
        }
        __syncthreads();
        if (c < 3) {
#pragma unroll
            for (int i = 0; i < 4; i++)
                ld[i] = *(const float4*)&src[(size_t)(i * 8 + wv) * HH + (c + 1) * 256 + l * 4];
        }
        const int kw = c * 256 + wv * 32 + ks * 4;
        const int kb = wv * 8 + ks;
        float4 h4[4];
#pragma unroll
        for (int e = 0; e < 4; e++) {
            int b = bg * 4 + e;
            h4[e] = *(const float4*)&stgL[b * 256 + ((kb ^ ((b >> 2) & 7)) << 2)];
        }
#pragma unroll
        for (int r = 0; r < 12; r++) {
            float4 w4 = *(const float4*)&wAll[wrow + r][kw];
#pragma unroll
            for (int e = 0; e < 4; e++) {
                acc[r][e] = fmaf(w4.x, h4[e].x, acc[r][e]);
                acc[r][e] = fmaf(w4.y, h4[e].y, acc[r][e]);
                acc[r][e] = fmaf(w4.z, h4[e].z, acc[r][e]);
                acc[r][e] = fmaf(w4.w, h4[e].w, acc[r][e]);
            }
        }
    }
#pragma unroll
    for (int r = 0; r < 12; r++)
#pragma unroll
        for (int e = 0; e < 4; e++) {
            float v = acc[r][e];
            v += __shfl_xor(v, 16, 64);
            v += __shfl_xor(v, 32, 64);
            acc[r][e] = v;
        }
    if (l < 16) {
        int s = l >> 3, bgw = l & 7;
#pragma unroll
        for (int r = 0; r < 12; r++) {
            float4 o = make_float4(acc[r][0], acc[r][1], acc[r][2], acc[r][3]);
            *(float4*)&part[wv * 2 + s][r][bgw * 4] = o;
        }
    }
}

// ---------------------------------------------------------------------------
// Fallback-only scan (ws too small for chunked path). Unchanged.
// ---------------------------------------------------------------------------
template<int IN_DIM>
__global__ __launch_bounds__(512, 2) void k_scan(
    const float* __restrict__ xsrc,
    const float* __restrict__ Wih,
    const float* __restrict__ Whh,
    const float* __restrict__ bih,
    const float* __restrict__ bhh,
    float* __restrict__ y,
    int* __restrict__ barx,
    float* __restrict__ pool)
{
    __shared__ float wAll[24][HH];
    __shared__ float stgL[32 * 256];
    __shared__ float part[16][12][32];
    __shared__ float bi[12], bh[12];
    __shared__ double pool_l[128];

    const int tid = threadIdx.x;
    const int j0 = blockIdx.x * 4;

    for (int i = tid; i < 12 * 256; i += 512) {
        int r = i >> 8, c4 = (i & 255) * 4;
        int g = r >> 2, jj = r & 3;
        *(float4*)&wAll[r][c4] =
            *(const float4*)&Whh[(size_t)(g * HH + j0 + jj) * HH + c4];
    }
    if (IN_DIM == HH) {
        for (int i = tid; i < 12 * 256; i += 512) {
            int r = i >> 8, c4 = (i & 255) * 4;
            int g = r >> 2, jj = r & 3;
            *(float4*)&wAll[12 + r][c4] =
                *(const float4*)&Wih[(size_t)(g * HH + j0 + jj) * HH + c4];
        }
    } else {
        if (tid < 96) {
            int r = tid >> 3, d = tid & 7;
            int g = r >> 2, jj = r & 3;
            wAll[12 + r][d] = Wih[(size_t)(g * HH + j0 + jj) * IN_DIM + d];
        }
    }
    if (tid < 12) {
        int g = tid >> 2, jj = tid & 3;
        bi[tid] = bih[g * HH + j0 + jj];
        bh[tid] = bhh[g * HH + j0 + jj];
    }
    if (tid < 128) pool_l[tid] = 0.0;
    __syncthreads();

    float hp_reg = 0.f;
    for (int t = 0; t < TT; t++) {
        double ig0 = 0.0, ig1 = 0.0, ig2 = 0.0;
        if (IN_DIM == HH) {
            mv_phase(wAll, stgL, part, xsrc + (size_t)t * BB * HH, 12, tid);
            __syncthreads();
            if (tid < 128) {
                int b = tid >> 2, jj = tid & 3;
                ig0 = bi[jj]; ig1 = bi[4 + jj]; ig2 = bi[8 + jj];
#pragma unroll
                for (int p = 0; p < 16; p++) {
                    ig0 += part[p][jj][b];
                    ig1 += part[p][4 + jj][b];
                    ig2 += part[p][8 + jj][b];
                }
            }
        }
        if (t > 0) {
            if (tid < 8) {
                const int target = 32 * t;
                while (__hip_atomic_load(&barx[tid * 16], __ATOMIC_RELAXED,
                                         __HIP_MEMORY_SCOPE_AGENT) < target)
                    __builtin_amdgcn_s_sleep(1);
            }
            __syncthreads();
            mv_phase(wAll, stgL, part, y + (size_t)(t - 1) * BB * HH, 0, tid);
            __syncthreads();
        }
        if (tid < 128) {
            int b = tid >> 2, jj = tid & 3, jg = j0 + jj;
            double hg0 = bh[jj], hg1 = bh[4 + jj], hg2 = bh[8 + jj];
            if (t > 0) {
#pragma unroll
                for (int p = 0; p < 16; p++) {
                    hg0 += part[p][jj][b];
                    hg1 += part[p][4 + jj][b];
                    hg2 += part[p][8 + jj][b];
                }
            }
            if (IN_DIM != HH) {
                const float* xp = xsrc + ((size_t)b * TT + t) * IN_DIM;
                float xv[8];
                *(float4*)&xv[0] = *(const float4*)&xp[0];
                *(float4*)&xv[4] = *(const float4*)&xp[4];
                float s0 = 0.f, s1 = 0.f, s2 = 0.f;
#pragma unroll
                for (int d = 0; d < 8; d++) {
                    s0 = fmaf(wAll[12 + jj][d], xv[d], s0);
                    s1 = fmaf(wAll[16 + jj][d], xv[d], s1);
                    s2 = fmaf(wAll[20 + jj][d], xv[d], s2);
                }
                ig0 = (double)bi[jj] + s0;
                ig1 = (double)bi[4 + jj] + s1;
                ig2 = (double)bi[8 + jj] + s2;
            }
            float rr = 1.f / (1.f + expf(-(float)(ig0 + hg0)));
            float zz = 1.f / (1.f + expf(-(float)(ig1 + hg1)));
            float nn = tanhf((float)(ig2 + (double)rr * hg2));
            float hnew = (1.f - zz) * nn + zz * hp_reg;
            hp_reg = hnew;
            __hip_atomic_store(&y[(size_t)t * BB * HH + b * HH + jg], hnew,
                               __ATOMIC_RELAXED, __HIP_MEMORY_SCOPE_AGENT);
            if (pool != nullptr) pool_l[tid] += (double)hnew;
        }
        if (t < TT - 1) {
            __syncthreads();
            if (tid == 0)
                __hip_atomic_fetch_add(&barx[(blockIdx.x & 7) * 16], 1,
                                       __ATOMIC_RELAXED, __HIP_MEMORY_SCOPE_AGENT);
        }
    }
    __syncthreads();
    if (pool != nullptr && tid < 128) {
        int b = tid >> 2, jj = tid & 3;
        pool[b * HH + j0 + jj] = (float)(pool_l[tid] * (1.0 / 512.0));
    }
}

// ---------------------------------------------------------------------------
// Hidden-only CHUNKED scan, r18: back to 512 threads (r16 structure, best
// known 2.49ms) + EARLY SIGNAL. Gate phase runs entirely in wave 0 (each
// lane owns 2 of the 128 (b,jj) outputs); after its 2 y-stores wave 0 does a
// wave-local s_waitcnt vmcnt(0) and lane 0 signals the flag IMMEDIATELY --
// no block-wide rendezvous on the signal path (trailing __syncthreads gone;
// per-step syncs 3->2). WAR on part[] is safe: waves 1-7 cannot pass the
// NEXT step's post-poll __syncthreads until wave 0 (which signals first)
// arrives. Pool accumulators live in wave-0 registers (pool_l removed).
// ---------------------------------------------------------------------------
__global__ __launch_bounds__(512, 1) void k_scan_x(
    const float* __restrict__ xg,
    const float* __restrict__ Whh,
    const float* __restrict__ bhh,
    float* __restrict__ y,
    int* __restrict__ flagx,          // [256] per-block step flags (zeroed)
    double* __restrict__ pool,
    int t0, int t1)
{
    __shared__ float wAll[12][HH];        // 48 KB
    __shared__ float part[16][12][32];    // 24.6 KB
    __shared__ float bh[12];

    const int tid = threadIdx.x;
    const int j0 = blockIdx.x * 4;
    const int wv = tid >> 6, l = tid & 63;
    const int ks = l >> 3, bg = l & 7;

    for (int i = tid; i < 12 * 256; i += 512) {
        int r = i >> 8, c4 = (i & 255) * 4;
        int g = r >> 2, jj = r & 3;
        *(float4*)&wAll[r][c4] =
            *(const float4*)&Whh[(size_t)(g * HH + j0 + jj) * HH + c4];
    }
    if (tid < 12) bh[tid] = bhh[(tid >> 2) * HH + j0 + (tid & 3)];

    // wave-0 gate ownership: lane handles (b2, jb) and (b2, jb+1)
    const int b2 = tid >> 1, jb = (tid & 1) * 2;
    float hp0 = 0.f, hp1 = 0.f;
    double pacc0 = 0.0, pacc1 = 0.0;
    if (t0 > 0 && tid < 64) {
        hp0 = y[(size_t)(t0 - 1) * BB * HH + b2 * HH + j0 + jb];
        hp1 = y[(size_t)(t0 - 1) * BB * HH + b2 * HH + j0 + jb + 1];
    }
    __syncthreads();

    for (int t = t0; t < t1; t++) {
        // prefetch this step's input gates (wave 0 only) before the poll
        float xr0 = 0.f, xz0 = 0.f, xn0 = 0.f;
        float xr1 = 0.f, xz1 = 0.f, xn1 = 0.f;
        if (tid < 64) {
            const float* xrow = xg + ((size_t)(t - t0) * BB + b2) * G3;
            xr0 = xrow[j0 + jb];          xr1 = xrow[j0 + jb + 1];
            xz0 = xrow[HH + j0 + jb];     xz1 = xrow[HH + j0 + jb + 1];
            xn0 = xrow[2 * HH + j0 + jb]; xn1 = xrow[2 * HH + j0 + jb + 1];
        }
        if (t > t0) {
            if (tid < 64) {                      // wave 0 polls all 256 flags
                const int target = t - t0;
                const int* fp = flagx + tid * 4;
                for (;;) {
                    int f0 = __hip_atomic_load(fp + 0, __ATOMIC_RELAXED,
                                               __HIP_MEMORY_SCOPE_AGENT);
                    int f1 = __hip_atomic_load(fp + 1, __ATOMIC_RELAXED,
                                               __HIP_MEMORY_SCOPE_AGENT);
                    int f2 = __hip_atomic_load(fp + 2, __ATOMIC_RELAXED,
                                               __HIP_MEMORY_SCOPE_AGENT);
                    int f3 = __hip_atomic_load(fp + 3, __ATOMIC_RELAXED,
                                               __HIP_MEMORY_SCOPE_AGENT);
                    int m01 = f0 < f1 ? f0 : f1;
                    int m23 = f2 < f3 ? f2 : f3;
                    int m = m01 < m23 ? m01 : m23;
                    if (__all(m >= target)) break;
                    __builtin_amdgcn_s_sleep(1);
                }
            }
            __syncthreads();
        }
        if (t > 0) {
            const float* hsrc = y + (size_t)(t - 1) * BB * HH;
            float4 hr[4][4];
#pragma unroll
            for (int c = 0; c < 4; c++)
#pragma unroll
                for (int e = 0; e < 4; e++)
                    hr[c][e] = *(const float4*)
                        &hsrc[(size_t)(bg * 4 + e) * HH + c * 256 + wv * 32 + ks * 4];

            float acc[12][4];
#pragma unroll
            for (int r = 0; r < 12; r++) {
                acc[r][0] = 0.f; acc[r][1] = 0.f; acc[r][2] = 0.f; acc[r][3] = 0.f;
            }
#pragma unroll
            for (int c = 0; c < 4; c++) {
                const int kw = c * 256 + wv * 32 + ks * 4;
#pragma unroll
                for (int r = 0; r < 12; r++) {
                    float4 w4 = *(const float4*)&wAll[r][kw];
#pragma unroll
                    for (int e = 0; e < 4; e++) {
                        acc[r][e] = fmaf(w4.x, hr[c][e].x, acc[r][e]);
                        acc[r][e] = fmaf(w4.y, hr[c][e].y, acc[r][e]);
                        acc[r][e] = fmaf(w4.z, hr[c][e].z, acc[r][e]);
                        acc[r][e] = fmaf(w4.w, hr[c][e].w, acc[r][e]);
                    }
                }
            }
#pragma unroll
            for (int r = 0; r < 12; r++)
#pragma unroll
                for (int e = 0; e < 4; e++) {
                    float v = acc[r][e];
                    v += __shfl_xor(v, 16, 64);
                    v += __shfl_xor(v, 32, 64);
                    acc[r][e] = v;
                }
            if (l < 16) {
                int s = l >> 3, bgw = l & 7;
#pragma unroll
                for (int r = 0; r < 12; r++) {
                    float4 o = make_float4(acc[r][0], acc[r][1], acc[r][2], acc[r][3]);
                    *(float4*)&part[wv * 2 + s][r][bgw * 4] = o;
                }
            }
            __syncthreads();
        }
        if (tid < 64) {
            double hgA0 = bh[jb], hgA1 = bh[4 + jb], hgA2 = bh[8 + jb];
            double hgB0 = bh[jb + 1], hgB1 = bh[4 + jb + 1], hgB2 = bh[8 + jb + 1];
            if (t > 0) {
#pragma unroll
                for (int p = 0; p < 16; p++) {
                    hgA0 += part[p][jb][b2];
                    hgA1 += part[p][4 + jb][b2];
                    hgA2 += part[p][8 + jb][b2];
                    hgB0 += part[p][jb + 1][b2];
                    hgB1 += part[p][4 + jb + 1][b2];
                    hgB2 += part[p][8 + jb + 1][b2];
                }
            }
            float rA = 1.f / (1.f + expf(-(xr0 + (float)hgA0)));
            float zA = 1.f / (1.f + expf(-(xz0 + (float)hgA1)));
            float nA = tanhf(xn0 + rA * (float)hgA2);
            float h0 = (1.f - zA) * nA + zA * hp0;
            float rB = 1.f / (1.f + expf(-(xr1 + (float)hgB0)));
            float zB = 1.f / (1.f + expf(-(xz1 + (float)hgB1)));
            float nB = tanhf(xn1 + rB * (float)hgB2);
            float h1 = (1.f - zB) * nB + zB * hp1;
            hp0 = h0; hp1 = h1;
            float* yrow = y + (size_t)t * BB * HH + b2 * HH + j0 + jb;
            __hip_atomic_store(yrow, h0, __ATOMIC_RELAXED, __HIP_MEMORY_SCOPE_AGENT);
            __hip_atomic_store(yrow + 1, h1, __ATOMIC_RELAXED, __HIP_MEMORY_SCOPE_AGENT);
            if (pool != nullptr) { pacc0 += (double)h0; pacc1 += (double)h1; }
            if (t < t1 - 1) {
                // wave-local drain of this wave's y stores, then signal.
                asm volatile("s_waitcnt vmcnt(0)" ::: "memory");
                if (tid == 0)
                    __hip_atomic_store(&flagx[blockIdx.x], t - t0 + 1,
                                       __ATOMIC_RELAXED, __HIP_MEMORY_SCOPE_AGENT);
            }
        }
    }
    if (pool != nullptr && tid < 64) {
        pool[b2 * HH + j0 + jb]     += pacc0;
        pool[b2 * HH + j0 + jb + 1] += pacc1;
    }
}

// ---------------------------------------------------------------------------
// pooled_f[i] = pooled_d[i] / 512
// ---------------------------------------------------------------------------
__global__ __launch_bounds__(512) void k_poolfin(const double* __restrict__ pd,
                                                 float* __restrict__ pf)
{
    int i = blockIdx.x * 512 + threadIdx.x;
    if (i < BB * HH) pf[i] = (float)(pd[i] * (1.0 / 512.0));
}

// ---------------------------------------------------------------------------
// xg GEMM (layers 1,2): C[m][n] = sum_k A[m][k]*Bw[n][k] + bias[n]
// 128x128 tile, BK=16, 256 threads, 8x8 microtile.
// ---------------------------------------------------------------------------
__global__ __launch_bounds__(256, 2) void k_gemm_xg(const float* __restrict__ A,
                                                    const float* __restrict__ Bw,
                                                    const float* __restrict__ bias,
                                                    float* __restrict__ C)
{
    __shared__ float As[16][132];
    __shared__ float Bs[16][132];
    const int tid = threadIdx.x;
    const int tx = tid & 15, ty = tid >> 4;
    const int bm = blockIdx.x * 128, bn = blockIdx.y * 128;
    float acc[8][8];
#pragma unroll
    for (int i = 0; i < 8; i++)
#pragma unroll
        for (int j = 0; j < 8; j++) acc[i][j] = 0.f;

    const int srow = tid >> 1, sch = (tid & 1) * 8;
    for (int k0 = 0; k0 < HH; k0 += 16) {
        {
            const float* ap = &A[(size_t)(bm + srow) * HH + k0 + sch];
            float4 v0 = *(const float4*)ap;
            float4 v1 = *(const float4*)(ap + 4);
            As[sch + 0][srow] = v0.x; As[sch + 1][srow] = v0.y;
            As[sch + 2][srow] = v0.z; As[sch + 3][srow] = v0.w;
            As[sch + 4][srow] = v1.x; As[sch + 5][srow] = v1.y;
            As[sch + 6][srow] = v1.z; As[sch + 7][srow] = v1.w;
            const float* bp = &Bw[(size_t)(bn + srow) * HH + k0 + sch];
            float4 u0 = *(const float4*)bp;
            float4 u1 = *(const float4*)(bp + 4);
            Bs[sch + 0][srow] = u0.x; Bs[sch + 1][srow] = u0.y;
            Bs[sch + 2][srow] = u0.z; Bs[sch + 3][srow] = u0.w;
            Bs[sch + 4][srow] = u1.x; Bs[sch + 5][srow] = u1.y;
            Bs[sch + 6][srow] = u1.z; Bs[sch + 7][srow] = u1.w;
        }
        __syncthreads();
#pragma unroll
        for (int k = 0; k < 16; k++) {
            float a[8], b[8];
            *(float4*)&a[0] = *(const float4*)&As[k][ty * 8];
            *(float4*)&a[4] = *(const float4*)&As[k][ty * 8 + 4];
            *(float4*)&b[0] = *(const float4*)&Bs[k][tx * 8];
            *(float4*)&b[4] = *(const float4*)&Bs[k][tx * 8 + 4];
#pragma unroll
            for (int i = 0; i < 8; i++)
#pragma unroll
                for (int j = 0; j < 8; j++)
                    acc[i][j] = fmaf(a[i], b[j], acc[i][j]);
        }
        __syncthreads();
    }
#pragma unroll
    for (int i = 0; i < 8; i++) {
        float o[8];
#pragma unroll
        for (int j = 0; j < 8; j++) o[j] = acc[i][j] + bias[bn + tx * 8 + j];
        float* cp = &C[(size_t)(bm + ty * 8 + i) * G3 + bn + tx * 8];
        *(float4*)cp = *(float4*)&o[0];
        *(float4*)(cp + 4) = *(float4*)&o[4];
    }
}

// ---------------------------------------------------------------------------
// xg GEMM for layer 0 (K=8): C[m][n] = sum_{k<8} x[b][t][k]*W[n][k] + bias[n]
// m local to chunk: m = (t-t0)*32 + b. Grid (CH*32/128, 24), 256 threads.
// ---------------------------------------------------------------------------
__global__ __launch_bounds__(256) void k_gemm_xg0(const float* __restrict__ x,
                                                  const float* __restrict__ W,
                                                  const float* __restrict__ bias,
                                                  float* __restrict__ C,
                                                  int t0)
{
    __shared__ float As[128][8];
    __shared__ float Bs[128][8];
    const int tid = threadIdx.x;
    const int bm = blockIdx.x * 128, bn = blockIdx.y * 128;
    {
        int r = tid >> 1, hf = (tid & 1) * 4;
        int m = bm + r;                       // chunk-local row
        int b = m & 31, tt = t0 + (m >> 5);
        *(float4*)&As[r][hf] = *(const float4*)&x[((size_t)b * TT + tt) * 8 + hf];
        *(float4*)&Bs[r][hf] = *(const float4*)&W[(size_t)(bn + r) * 8 + hf];
    }
    __syncthreads();
    const int tx = tid & 15, ty = tid >> 4;
    float acc[8][8];
#pragma unroll
    for (int i = 0; i < 8; i++)
#pragma unroll
        for (int j = 0; j < 8; j++) acc[i][j] = 0.f;
#pragma unroll
    for (int k = 0; k < 8; k++) {
        float a[8], b[8];
#pragma unroll
        for (int i = 0; i < 8; i++) a[i] = As[ty * 8 + i][k];
#pragma unroll
        for (int j = 0; j < 8; j++) b[j] = Bs[tx * 8 + j][k];
#pragma unroll
        for (int i = 0; i < 8; i++)
#pragma unroll
            for (int j = 0; j < 8; j++)
                acc[i][j] = fmaf(a[i], b[j], acc[i][j]);
    }
#pragma unroll
    for (int i = 0; i < 8; i++) {
        float o[8];
#pragma unroll
        for (int j = 0; j < 8; j++) o[j] = acc[i][j] + bias[bn + tx * 8 + j];
        float* cp = &C[(size_t)(bm + ty * 8 + i) * G3 + bn + tx * 8];
        *(float4*)cp = *(float4*)&o[0];
        *(float4*)(cp + 4) = *(float4*)&o[4];
    }
}

// ---------------------------------------------------------------------------
__global__ __launch_bounds__(256) void k_fc(const float* __restrict__ in,
                                            const float* __restrict__ w,
                                            const float* __restrict__ bias,
                                            float* __restrict__ out,
                                            int ind, int outd, int dorelu)
{
    int b = blockIdx.y;
    int o = blockIdx.x * 256 + threadIdx.x;
    if (o >= outd) return;
    const float* ip = in + (size_t)b * ind;
    const float* wp = w + (size_t)o * ind;
    double s = (double)bias[o];
    for (int k = 0; k < ind; k += 4) {
        float4 wv = *(const float4*)&wp[k];
        float4 iv = *(const float4*)&ip[k];
        s += (double)iv.x * wv.x + (double)iv.y * wv.y
           + (double)iv.z * wv.z + (double)iv.w * wv.w;
    }
    float v = (float)s;
    if (dorelu) v = fmaxf(v, 0.f);
    out[(size_t)b * outd + o] = v;
}

// ---------------------------------------------------------------------------
extern "C" void kernel_launch(void* const* d_in, const int* in_sizes, int n_in,
                              void* d_out, int out_size, void* d_ws, size_t ws_size,
                              hipStream_t stream)
{
    (void)in_sizes; (void)n_in; (void)out_size;
    const float* x    = (const float*)d_in[0];
    const float* Wih[3] = {(const float*)d_in[1], (const float*)d_in[5], (const float*)d_in[9]};
    const float* Whh[3] = {(const float*)d_in[2], (const float*)d_in[6], (const float*)d_in[10]};
    const float* bih[3] = {(const float*)d_in[3], (const float*)d_in[7], (const float*)d_in[11]};
    const float* bhh[3] = {(const float*)d_in[4], (const float*)d_in[8], (const float*)d_in[12]};
    const float* fc1w = (const float*)d_in[13];
    const float* fc1b = (const float*)d_in[14];
    const float* fc2w = (const float*)d_in[15];
    const float* fc2b = (const float*)d_in[16];
    const float* fc3w = (const float*)d_in[17];
    const float* fc3b = (const float*)d_in[18];

    // workspace layout
    int*    bars     = (int*)d_ws;                 // 96 x 128 ints (fallback)
    int*    flags    = bars + 96 * 128;            // 96 x 256 ints (scan_x)
    double* pooled_d = (double*)(flags + 96 * 256);   // 256 KB
    float*  pooled_f = (float*)(pooled_d + BB * HH);  // 128 KB
    float*  fc1o     = pooled_f + BB * HH;
    float*  fc2o     = fc1o + BB * 512;
    float*  y0       = fc2o + BB * 256;               // 67.1 MB
    float*  y1       = y0 + (size_t)TT * BB * HH;     // 67.1 MB
    float*  xg       = y1 + (size_t)TT * BB * HH;     // CH*393 KB

    const size_t base = (size_t)((char*)xg - (char*)d_ws);
    if (ws_size < base) return;

    int CH = 0;
    for (int c = 512; c >= 16; c >>= 1) {
        if (base + (size_t)c * BB * G3 * 4 <= ws_size) { CH = c; break; }
    }

    hipMemsetAsync(bars, 0, (96 * 128 + 96 * 256) * sizeof(int), stream);
    hipMemsetAsync(pooled_d, 0, BB * HH * sizeof(double), stream);

    int binst = 0;
    if (CH > 0) {
        // layer 0: K=8 gemm + hidden-only scan (same structure as layers 1,2)
        for (int t0 = 0; t0 < TT; t0 += CH) {
            k_gemm_xg0<<<dim3(CH * BB / 128, G3 / 128), 256, 0, stream>>>(
                x, Wih[0], bih[0], xg, t0);
            k_scan_x<<<256, 512, 0, stream>>>(
                xg, Whh[0], bhh[0], y0, flags + (binst++) * 256, nullptr, t0, t0 + CH);
        }
        float* ybuf[2] = {y0, y1};
        for (int l = 1; l <= 2; l++) {
            const float* src = ybuf[(l - 1) & 1];
            float* dst = ybuf[l & 1];   // layer 2 reuses y0
            double* pl = (l == 2) ? pooled_d : nullptr;
            for (int t0 = 0; t0 < TT; t0 += CH) {
                k_gemm_xg<<<dim3(CH * BB / 128, G3 / 128), 256, 0, stream>>>(
                    src + (size_t)t0 * BB * HH, Wih[l], bih[l], xg);
                k_scan_x<<<256, 512, 0, stream>>>(
                    xg, Whh[l], bhh[l], dst, flags + (binst++) * 256, pl, t0, t0 + CH);
            }
        }
        k_poolfin<<<(BB * HH + 511) / 512, 512, 0, stream>>>(pooled_d, pooled_f);
        k_fc<<<dim3(2, 32), 256, 0, stream>>>(pooled_f, fc1w, fc1b, fc1o, HH, 512, 1);
    } else {
        // fallback (never expected: ws >= 235 MB proven in round 10)
        float* pooled_fb = pooled_f;
        k_scan<8><<<256, 512, 0, stream>>>(x, Wih[0], Whh[0], bih[0], bhh[0], y0,
                                           bars + (binst++) * 128, nullptr);
        k_scan<HH><<<256, 512, 0, stream>>>(y0, Wih[1], Whh[1], bih[1], bhh[1], y1,
                                            bars + (binst++) * 128, nullptr);
        k_scan<HH><<<256, 512, 0, stream>>>(y1, Wih[2], Whh[2], bih[2], bhh[2], y0,
                                            bars + (binst++) * 128, pooled_fb);
        k_fc<<<dim3(2, 32), 256, 0, stream>>>(pooled_fb, fc1w, fc1b, fc1o, HH, 512, 1);
    }

    k_fc<<<dim3(1, 32), 256, 0, stream>>>(fc1o, fc2w, fc2b, fc2o, 512, 256, 1);
    k_fc<<<dim3(1, 32), 256, 0, stream>>>(fc2o, fc3w, fc3b, (float*)d_out, 256, 1, 0);
}

// Round 19
// 17347.299 us; speedup vs baseline: 1.2786x; 1.0680x over previous
//
#include <hip/hip_runtime.h>
#include <cmath>

#define TT 512
#define BB 32
#define HH 1024
#define G3 3072

// ---------------------------------------------------------------------------
// mv_phase (fallback k_scan only): LDS-staged matvec, round-6 structure.
// ---------------------------------------------------------------------------
__device__ __forceinline__ void mv_phase(
    float (*wAll)[HH],              // rows [wrow, wrow+12)
    float* stgL,                    // [32*256]
    float (*part)[12][32],          // [16][12][32]
    const float* __restrict__ src,  // [32][1024] row-major
    int wrow, int tid)
{
    const int wv = tid >> 6, l = tid & 63;
    const int ks = l >> 3, bg = l & 7;
    float acc[12][4];
#pragma unroll
    for (int r = 0; r < 12; r++) {
        acc[r][0] = 0.f; acc[r][1] = 0.f; acc[r][2] = 0.f; acc[r][3] = 0.f;
    }

    float4 ld[4];
#pragma unroll
    for (int i = 0; i < 4; i++)
        ld[i] = *(const float4*)&src[(size_t)(i * 8 + wv) * HH + l * 4];

#pragma unroll
    for (int c = 0; c < 4; c++) {
        __syncthreads();
#pragma unroll
        for (int i = 0; i < 4; i++) {
            int b = i * 8 + wv;
            *(float4*)&stgL[b * 256 + ((l ^ ((b >> 2) & 7)) << 2)] = ld[i];
        }
        __syncthreads();
        if (c < 3) {
#pragma unroll
            for (int i = 0; i < 4; i++)
                ld[i] = *(const float4*)&src[(size_t)(i * 8 + wv) * HH + (c + 1) * 256 + l * 4];
        }
        const int kw = c * 256 + wv * 32 + ks * 4;
        const int kb = wv * 8 + ks;
        float4 h4[4];
#pragma unroll
        for (int e = 0; e < 4; e++) {
            int b = bg * 4 + e;
            h4[e] = *(const float4*)&stgL[b * 256 + ((kb ^ ((b >> 2) & 7)) << 2)];
        }
#pragma unroll
        for (int r = 0; r < 12; r++) {
            float4 w4 = *(const float4*)&wAll[wrow + r][kw];
#pragma unroll
            for (int e = 0; e < 4; e++) {
                acc[r][e] = fmaf(w4.x, h4[e].x, acc[r][e]);
                acc[r][e] = fmaf(w4.y, h4[e].y, acc[r][e]);
                acc[r][e] = fmaf(w4.z, h4[e].z, acc[r][e]);
                acc[r][e] = fmaf(w4.w, h4[e].w, acc[r][e]);
            }
        }
    }
#pragma unroll
    for (int r = 0; r < 12; r++)
#pragma unroll
        for (int e = 0; e < 4; e++) {
            float v = acc[r][e];
            v += __shfl_xor(v, 16, 64);
            v += __shfl_xor(v, 32, 64);
            acc[r][e] = v;
        }
    if (l < 16) {
        int s = l >> 3, bgw = l & 7;
#pragma unroll
        for (int r = 0; r < 12; r++) {
            float4 o = make_float4(acc[r][0], acc[r][1], acc[r][2], acc[r][3]);
            *(float4*)&part[wv * 2 + s][r][bgw * 4] = o;
        }
    }
}

// ---------------------------------------------------------------------------
// Fallback-only scan (ws too small for chunked path). Unchanged.
// ---------------------------------------------------------------------------
template<int IN_DIM>
__global__ __launch_bounds__(512, 2) void k_scan(
    const float* __restrict__ xsrc,
    const float* __restrict__ Wih,
    const float* __restrict__ Whh,
    const float* __restrict__ bih,
    const float* __restrict__ bhh,
    float* __restrict__ y,
    int* __restrict__ barx,
    float* __restrict__ pool)
{
    __shared__ float wAll[24][HH];
    __shared__ float stgL[32 * 256];
    __shared__ float part[16][12][32];
    __shared__ float bi[12], bh[12];
    __shared__ double pool_l[128];

    const int tid = threadIdx.x;
    const int j0 = blockIdx.x * 4;

    for (int i = tid; i < 12 * 256; i += 512) {
        int r = i >> 8, c4 = (i & 255) * 4;
        int g = r >> 2, jj = r & 3;
        *(float4*)&wAll[r][c4] =
            *(const float4*)&Whh[(size_t)(g * HH + j0 + jj) * HH + c4];
    }
    if (IN_DIM == HH) {
        for (int i = tid; i < 12 * 256; i += 512) {
            int r = i >> 8, c4 = (i & 255) * 4;
            int g = r >> 2, jj = r & 3;
            *(float4*)&wAll[12 + r][c4] =
                *(const float4*)&Wih[(size_t)(g * HH + j0 + jj) * HH + c4];
        }
    } else {
        if (tid < 96) {
            int r = tid >> 3, d = tid & 7;
            int g = r >> 2, jj = r & 3;
            wAll[12 + r][d] = Wih[(size_t)(g * HH + j0 + jj) * IN_DIM + d];
        }
    }
    if (tid < 12) {
        int g = tid >> 2, jj = tid & 3;
        bi[tid] = bih[g * HH + j0 + jj];
        bh[tid] = bhh[g * HH + j0 + jj];
    }
    if (tid < 128) pool_l[tid] = 0.0;
    __syncthreads();

    float hp_reg = 0.f;
    for (int t = 0; t < TT; t++) {
        double ig0 = 0.0, ig1 = 0.0, ig2 = 0.0;
        if (IN_DIM == HH) {
            mv_phase(wAll, stgL, part, xsrc + (size_t)t * BB * HH, 12, tid);
            __syncthreads();
            if (tid < 128) {
                int b = tid >> 2, jj = tid & 3;
                ig0 = bi[jj]; ig1 = bi[4 + jj]; ig2 = bi[8 + jj];
#pragma unroll
                for (int p = 0; p < 16; p++) {
                    ig0 += part[p][jj][b];
                    ig1 += part[p][4 + jj][b];
                    ig2 += part[p][8 + jj][b];
                }
            }
        }
        if (t > 0) {
            if (tid < 8) {
                const int target = 32 * t;
                while (__hip_atomic_load(&barx[tid * 16], __ATOMIC_RELAXED,
                                         __HIP_MEMORY_SCOPE_AGENT) < target)
                    __builtin_amdgcn_s_sleep(1);
            }
            __syncthreads();
            mv_phase(wAll, stgL, part, y + (size_t)(t - 1) * BB * HH, 0, tid);
            __syncthreads();
        }
        if (tid < 128) {
            int b = tid >> 2, jj = tid & 3, jg = j0 + jj;
            double hg0 = bh[jj], hg1 = bh[4 + jj], hg2 = bh[8 + jj];
            if (t > 0) {
#pragma unroll
                for (int p = 0; p < 16; p++) {
                    hg0 += part[p][jj][b];
                    hg1 += part[p][4 + jj][b];
                    hg2 += part[p][8 + jj][b];
                }
            }
            if (IN_DIM != HH) {
                const float* xp = xsrc + ((size_t)b * TT + t) * IN_DIM;
                float xv[8];
                *(float4*)&xv[0] = *(const float4*)&xp[0];
                *(float4*)&xv[4] = *(const float4*)&xp[4];
                float s0 = 0.f, s1 = 0.f, s2 = 0.f;
#pragma unroll
                for (int d = 0; d < 8; d++) {
                    s0 = fmaf(wAll[12 + jj][d], xv[d], s0);
                    s1 = fmaf(wAll[16 + jj][d], xv[d], s1);
                    s2 = fmaf(wAll[20 + jj][d], xv[d], s2);
                }
                ig0 = (double)bi[jj] + s0;
                ig1 = (double)bi[4 + jj] + s1;
                ig2 = (double)bi[8 + jj] + s2;
            }
            float rr = 1.f / (1.f + expf(-(float)(ig0 + hg0)));
            float zz = 1.f / (1.f + expf(-(float)(ig1 + hg1)));
            float nn = tanhf((float)(ig2 + (double)rr * hg2));
            float hnew = (1.f - zz) * nn + zz * hp_reg;
            hp_reg = hnew;
            __hip_atomic_store(&y[(size_t)t * BB * HH + b * HH + jg], hnew,
                               __ATOMIC_RELAXED, __HIP_MEMORY_SCOPE_AGENT);
            if (pool != nullptr) pool_l[tid] += (double)hnew;
        }
        if (t < TT - 1) {
            __syncthreads();
            if (tid == 0)
                __hip_atomic_fetch_add(&barx[(blockIdx.x & 7) * 16], 1,
                                       __ATOMIC_RELAXED, __HIP_MEMORY_SCOPE_AGENT);
        }
    }
    __syncthreads();
    if (pool != nullptr && tid < 128) {
        int b = tid >> 2, jj = tid & 3;
        pool[b * HH + j0 + jj] = (float)(pool_l[tid] * (1.0 / 512.0));
    }
}

// ---------------------------------------------------------------------------
// Hidden-only CHUNKED scan, r19: r16 structure (best: 2.49ms) + 2-FLAG early
// signal. Gate stays on 128 threads (waves 0,1; 1 output each). Each gate
// wave drains ITS OWN y stores (wave-local s_waitcnt vmcnt(0)) then signals
// its flag: wave0 -> flagx[bid], wave1 -> flagx[256+bid]. A&B >= target ==>
// all 128 h visible. No trailing block-wide sync on the signal path
// (syncs/step 3->2). WAR on part[] safe: waves 2-7 park at next poll-sync,
// reached by waves 0-1 only after signaling.
// ---------------------------------------------------------------------------
__global__ __launch_bounds__(512, 1) void k_scan_x(
    const float* __restrict__ xg,
    const float* __restrict__ Whh,
    const float* __restrict__ bhh,
    float* __restrict__ y,
    int* __restrict__ flagx,          // [512]: A=flagx[0..255], B=flagx[256..511]
    double* __restrict__ pool,
    int t0, int t1)
{
    __shared__ float wAll[12][HH];        // 48 KB
    __shared__ float part[16][12][32];    // 24.6 KB
    __shared__ float bh[12];
    __shared__ double pool_l[128];

    const int tid = threadIdx.x;
    const int j0 = blockIdx.x * 4;
    const int wv = tid >> 6, l = tid & 63;
    const int ks = l >> 3, bg = l & 7;

    for (int i = tid; i < 12 * 256; i += 512) {
        int r = i >> 8, c4 = (i & 255) * 4;
        int g = r >> 2, jj = r & 3;
        *(float4*)&wAll[r][c4] =
            *(const float4*)&Whh[(size_t)(g * HH + j0 + jj) * HH + c4];
    }
    if (tid < 12) bh[tid] = bhh[(tid >> 2) * HH + j0 + (tid & 3)];
    if (tid < 128) pool_l[tid] = 0.0;

    const int gb = tid >> 2, gjj = tid & 3;
    float hp_reg = 0.f;
    if (t0 > 0 && tid < 128)
        hp_reg = y[(size_t)(t0 - 1) * BB * HH + gb * HH + j0 + gjj];
    __syncthreads();

    for (int t = t0; t < t1; t++) {
        // prefetch this step's input gates before the barrier poll
        float xr = 0.f, xz = 0.f, xn = 0.f;
        if (tid < 128) {
            const float* xrow = xg + ((size_t)(t - t0) * BB + gb) * G3;
            xr = xrow[j0 + gjj];
            xz = xrow[HH + j0 + gjj];
            xn = xrow[2 * HH + j0 + gjj];
        }
        if (t > t0) {
            if (tid < 64) {                 // wave 0 polls all 512 flags
                const int target = t - t0;
                const int* fpA = flagx + tid * 4;
                const int* fpB = flagx + 256 + tid * 4;
                for (;;) {
                    int a0 = __hip_atomic_load(fpA + 0, __ATOMIC_RELAXED,
                                               __HIP_MEMORY_SCOPE_AGENT);
                    int a1 = __hip_atomic_load(fpA + 1, __ATOMIC_RELAXED,
                                               __HIP_MEMORY_SCOPE_AGENT);
                    int a2 = __hip_atomic_load(fpA + 2, __ATOMIC_RELAXED,
                                               __HIP_MEMORY_SCOPE_AGENT);
                    int a3 = __hip_atomic_load(fpA + 3, __ATOMIC_RELAXED,
                                               __HIP_MEMORY_SCOPE_AGENT);
                    int b0 = __hip_atomic_load(fpB + 0, __ATOMIC_RELAXED,
                                               __HIP_MEMORY_SCOPE_AGENT);
                    int b1 = __hip_atomic_load(fpB + 1, __ATOMIC_RELAXED,
                                               __HIP_MEMORY_SCOPE_AGENT);
                    int b2_ = __hip_atomic_load(fpB + 2, __ATOMIC_RELAXED,
                                                __HIP_MEMORY_SCOPE_AGENT);
                    int b3 = __hip_atomic_load(fpB + 3, __ATOMIC_RELAXED,
                                               __HIP_MEMORY_SCOPE_AGENT);
                    int m0 = a0 < a1 ? a0 : a1;
                    int m1 = a2 < a3 ? a2 : a3;
                    int m2 = b0 < b1 ? b0 : b1;
                    int m3 = b2_ < b3 ? b2_ : b3;
                    int mA = m0 < m1 ? m0 : m1;
                    int mB = m2 < m3 ? m2 : m3;
                    int m = mA < mB ? mA : mB;
                    if (__all(m >= target)) break;
                    __builtin_amdgcn_s_sleep(1);
                }
            }
            __syncthreads();
        }
        if (t > 0) {
            const float* hsrc = y + (size_t)(t - 1) * BB * HH;
            float4 hr[4][4];
#pragma unroll
            for (int c = 0; c < 4; c++)
#pragma unroll
                for (int e = 0; e < 4; e++)
                    hr[c][e] = *(const float4*)
                        &hsrc[(size_t)(bg * 4 + e) * HH + c * 256 + wv * 32 + ks * 4];

            float acc[12][4];
#pragma unroll
            for (int r = 0; r < 12; r++) {
                acc[r][0] = 0.f; acc[r][1] = 0.f; acc[r][2] = 0.f; acc[r][3] = 0.f;
            }
#pragma unroll
            for (int c = 0; c < 4; c++) {
                const int kw = c * 256 + wv * 32 + ks * 4;
#pragma unroll
                for (int r = 0; r < 12; r++) {
                    float4 w4 = *(const float4*)&wAll[r][kw];
#pragma unroll
                    for (int e = 0; e < 4; e++) {
                        acc[r][e] = fmaf(w4.x, hr[c][e].x, acc[r][e]);
                        acc[r][e] = fmaf(w4.y, hr[c][e].y, acc[r][e]);
                        acc[r][e] = fmaf(w4.z, hr[c][e].z, acc[r][e]);
                        acc[r][e] = fmaf(w4.w, hr[c][e].w, acc[r][e]);
                    }
                }
            }
#pragma unroll
            for (int r = 0; r < 12; r++)
#pragma unroll
                for (int e = 0; e < 4; e++) {
                    float v = acc[r][e];
                    v += __shfl_xor(v, 16, 64);
                    v += __shfl_xor(v, 32, 64);
                    acc[r][e] = v;
                }
            if (l < 16) {
                int s = l >> 3, bgw = l & 7;
#pragma unroll
                for (int r = 0; r < 12; r++) {
                    float4 o = make_float4(acc[r][0], acc[r][1], acc[r][2], acc[r][3]);
                    *(float4*)&part[wv * 2 + s][r][bgw * 4] = o;
                }
            }
            __syncthreads();
        }
        if (tid < 128) {
            double hg0 = bh[gjj], hg1 = bh[4 + gjj], hg2 = bh[8 + gjj];
            if (t > 0) {
#pragma unroll
                for (int p = 0; p < 16; p++) {
                    hg0 += part[p][gjj][gb];
                    hg1 += part[p][4 + gjj][gb];
                    hg2 += part[p][8 + gjj][gb];
                }
            }
            float rr = 1.f / (1.f + expf(-(xr + (float)hg0)));
            float zz = 1.f / (1.f + expf(-(xz + (float)hg1)));
            float nn = tanhf(xn + rr * (float)hg2);
            float hnew = (1.f - zz) * nn + zz * hp_reg;
            hp_reg = hnew;
            __hip_atomic_store(&y[(size_t)t * BB * HH + gb * HH + j0 + gjj], hnew,
                               __ATOMIC_RELAXED, __HIP_MEMORY_SCOPE_AGENT);
            if (pool != nullptr) pool_l[tid] += (double)hnew;
            if (t < t1 - 1) {
                // wave-local drain of THIS wave's y stores, then signal.
                asm volatile("s_waitcnt vmcnt(0)" ::: "memory");
                if (tid == 0)
                    __hip_atomic_store(&flagx[blockIdx.x], t - t0 + 1,
                                       __ATOMIC_RELAXED, __HIP_MEMORY_SCOPE_AGENT);
                if (tid == 64)
                    __hip_atomic_store(&flagx[256 + blockIdx.x], t - t0 + 1,
                                       __ATOMIC_RELAXED, __HIP_MEMORY_SCOPE_AGENT);
            }
        }
    }
    __syncthreads();
    if (pool != nullptr && tid < 128)
        pool[gb * HH + j0 + gjj] += pool_l[tid];   // serialized chunk kernels
}

// ---------------------------------------------------------------------------
// pooled_f[i] = pooled_d[i] / 512
// ---------------------------------------------------------------------------
__global__ __launch_bounds__(512) void k_poolfin(const double* __restrict__ pd,
                                                 float* __restrict__ pf)
{
    int i = blockIdx.x * 512 + threadIdx.x;
    if (i < BB * HH) pf[i] = (float)(pd[i] * (1.0 / 512.0));
}

// ---------------------------------------------------------------------------
// xg GEMM (layers 1,2): C[m][n] = sum_k A[m][k]*Bw[n][k] + bias[n]
// 128x128 tile, BK=16, 256 threads, 8x8 microtile.
// ---------------------------------------------------------------------------
__global__ __launch_bounds__(256, 2) void k_gemm_xg(const float* __restrict__ A,
                                                    const float* __restrict__ Bw,
                                                    const float* __restrict__ bias,
                                                    float* __restrict__ C)
{
    __shared__ float As[16][132];
    __shared__ float Bs[16][132];
    const int tid = threadIdx.x;
    const int tx = tid & 15, ty = tid >> 4;
    const int bm = blockIdx.x * 128, bn = blockIdx.y * 128;
    float acc[8][8];
#pragma unroll
    for (int i = 0; i < 8; i++)
#pragma unroll
        for (int j = 0; j < 8; j++) acc[i][j] = 0.f;

    const int srow = tid >> 1, sch = (tid & 1) * 8;
    for (int k0 = 0; k0 < HH; k0 += 16) {
        {
            const float* ap = &A[(size_t)(bm + srow) * HH + k0 + sch];
            float4 v0 = *(const float4*)ap;
            float4 v1 = *(const float4*)(ap + 4);
            As[sch + 0][srow] = v0.x; As[sch + 1][srow] = v0.y;
            As[sch + 2][srow] = v0.z; As[sch + 3][srow] = v0.w;
            As[sch + 4][srow] = v1.x; As[sch + 5][srow] = v1.y;
            As[sch + 6][srow] = v1.z; As[sch + 7][srow] = v1.w;
            const float* bp = &Bw[(size_t)(bn + srow) * HH + k0 + sch];
            float4 u0 = *(const float4*)bp;
            float4 u1 = *(const float4*)(bp + 4);
            Bs[sch + 0][srow] = u0.x; Bs[sch + 1][srow] = u0.y;
            Bs[sch + 2][srow] = u0.z; Bs[sch + 3][srow] = u0.w;
            Bs[sch + 4][srow] = u1.x; Bs[sch + 5][srow] = u1.y;
            Bs[sch + 6][srow] = u1.z; Bs[sch + 7][srow] = u1.w;
        }
        __syncthreads();
#pragma unroll
        for (int k = 0; k < 16; k++) {
            float a[8], b[8];
            *(float4*)&a[0] = *(const float4*)&As[k][ty * 8];
            *(float4*)&a[4] = *(const float4*)&As[k][ty * 8 + 4];
            *(float4*)&b[0] = *(const float4*)&Bs[k][tx * 8];
            *(float4*)&b[4] = *(const float4*)&Bs[k][tx * 8 + 4];
#pragma unroll
            for (int i = 0; i < 8; i++)
#pragma unroll
                for (int j = 0; j < 8; j++)
                    acc[i][j] = fmaf(a[i], b[j], acc[i][j]);
        }
        __syncthreads();
    }
#pragma unroll
    for (int i = 0; i < 8; i++) {
        float o[8];
#pragma unroll
        for (int j = 0; j < 8; j++) o[j] = acc[i][j] + bias[bn + tx * 8 + j];
        float* cp = &C[(size_t)(bm + ty * 8 + i) * G3 + bn + tx * 8];
        *(float4*)cp = *(float4*)&o[0];
        *(float4*)(cp + 4) = *(float4*)&o[4];
    }
}

// ---------------------------------------------------------------------------
// xg GEMM for layer 0 (K=8): C[m][n] = sum_{k<8} x[b][t][k]*W[n][k] + bias[n]
// m local to chunk: m = (t-t0)*32 + b. Grid (CH*32/128, 24), 256 threads.
// ---------------------------------------------------------------------------
__global__ __launch_bounds__(256) void k_gemm_xg0(const float* __restrict__ x,
                                                  const float* __restrict__ W,
                                                  const float* __restrict__ bias,
                                                  float* __restrict__ C,
                                                  int t0)
{
    __shared__ float As[128][8];
    __shared__ float Bs[128][8];
    const int tid = threadIdx.x;
    const int bm = blockIdx.x * 128, bn = blockIdx.y * 128;
    {
        int r = tid >> 1, hf = (tid & 1) * 4;
        int m = bm + r;                       // chunk-local row
        int b = m & 31, tt = t0 + (m >> 5);
        *(float4*)&As[r][hf] = *(const float4*)&x[((size_t)b * TT + tt) * 8 + hf];
        *(float4*)&Bs[r][hf] = *(const float4*)&W[(size_t)(bn + r) * 8 + hf];
    }
    __syncthreads();
    const int tx = tid & 15, ty = tid >> 4;
    float acc[8][8];
#pragma unroll
    for (int i = 0; i < 8; i++)
#pragma unroll
        for (int j = 0; j < 8; j++) acc[i][j] = 0.f;
#pragma unroll
    for (int k = 0; k < 8; k++) {
        float a[8], b[8];
#pragma unroll
        for (int i = 0; i < 8; i++) a[i] = As[ty * 8 + i][k];
#pragma unroll
        for (int j = 0; j < 8; j++) b[j] = Bs[tx * 8 + j][k];
#pragma unroll
        for (int i = 0; i < 8; i++)
#pragma unroll
            for (int j = 0; j < 8; j++)
                acc[i][j] = fmaf(a[i], b[j], acc[i][j]);
    }
#pragma unroll
    for (int i = 0; i < 8; i++) {
        float o[8];
#pragma unroll
        for (int j = 0; j < 8; j++) o[j] = acc[i][j] + bias[bn + tx * 8 + j];
        float* cp = &C[(size_t)(bm + ty * 8 + i) * G3 + bn + tx * 8];
        *(float4*)cp = *(float4*)&o[0];
        *(float4*)(cp + 4) = *(float4*)&o[4];
    }
}

// ---------------------------------------------------------------------------
__global__ __launch_bounds__(256) void k_fc(const float* __restrict__ in,
                                            const float* __restrict__ w,
                                            const float* __restrict__ bias,
                                            float* __restrict__ out,
                                            int ind, int outd, int dorelu)
{
    int b = blockIdx.y;
    int o = blockIdx.x * 256 + threadIdx.x;
    if (o >= outd) return;
    const float* ip = in + (size_t)b * ind;
    const float* wp = w + (size_t)o * ind;
    double s = (double)bias[o];
    for (int k = 0; k < ind; k += 4) {
        float4 wv = *(const float4*)&wp[k];
        float4 iv = *(const float4*)&ip[k];
        s += (double)iv.x * wv.x + (double)iv.y * wv.y
           + (double)iv.z * wv.z + (double)iv.w * wv.w;
    }
    float v = (float)s;
    if (dorelu) v = fmaxf(v, 0.f);
    out[(size_t)b * outd + o] = v;
}

// ---------------------------------------------------------------------------
extern "C" void kernel_launch(void* const* d_in, const int* in_sizes, int n_in,
                              void* d_out, int out_size, void* d_ws, size_t ws_size,
                              hipStream_t stream)
{
    (void)in_sizes; (void)n_in; (void)out_size;
    const float* x    = (const float*)d_in[0];
    const float* Wih[3] = {(const float*)d_in[1], (const float*)d_in[5], (const float*)d_in[9]};
    const float* Whh[3] = {(const float*)d_in[2], (const float*)d_in[6], (const float*)d_in[10]};
    const float* bih[3] = {(const float*)d_in[3], (const float*)d_in[7], (const float*)d_in[11]};
    const float* bhh[3] = {(const float*)d_in[4], (const float*)d_in[8], (const float*)d_in[12]};
    const float* fc1w = (const float*)d_in[13];
    const float* fc1b = (const float*)d_in[14];
    const float* fc2w = (const float*)d_in[15];
    const float* fc2b = (const float*)d_in[16];
    const float* fc3w = (const float*)d_in[17];
    const float* fc3b = (const float*)d_in[18];

    // workspace layout
    int*    bars     = (int*)d_ws;                 // 96 x 128 ints (fallback)
    int*    flags    = bars + 96 * 128;            // 96 x 512 ints (scan_x A/B)
    double* pooled_d = (double*)(flags + 96 * 512);   // 256 KB
    float*  pooled_f = (float*)(pooled_d + BB * HH);  // 128 KB
    float*  fc1o     = pooled_f + BB * HH;
    float*  fc2o     = fc1o + BB * 512;
    float*  y0       = fc2o + BB * 256;               // 67.1 MB
    float*  y1       = y0 + (size_t)TT * BB * HH;     // 67.1 MB
    float*  xg       = y1 + (size_t)TT * BB * HH;     // CH*393 KB

    const size_t base = (size_t)((char*)xg - (char*)d_ws);
    if (ws_size < base) return;

    int CH = 0;
    for (int c = 512; c >= 16; c >>= 1) {
        if (base + (size_t)c * BB * G3 * 4 <= ws_size) { CH = c; break; }
    }

    hipMemsetAsync(bars, 0, (96 * 128 + 96 * 512) * sizeof(int), stream);
    hipMemsetAsync(pooled_d, 0, BB * HH * sizeof(double), stream);

    int binst = 0;
    if (CH > 0) {
        // layer 0: K=8 gemm + hidden-only scan (same structure as layers 1,2)
        for (int t0 = 0; t0 < TT; t0 += CH) {
            k_gemm_xg0<<<dim3(CH * BB / 128, G3 / 128), 256, 0, stream>>>(
                x, Wih[0], bih[0], xg, t0);
            k_scan_x<<<256, 512, 0, stream>>>(
                xg, Whh[0], bhh[0], y0, flags + (binst++) * 512, nullptr, t0, t0 + CH);
        }
        float* ybuf[2] = {y0, y1};
        for (int l = 1; l <= 2; l++) {
            const float* src = ybuf[(l - 1) & 1];
            float* dst = ybuf[l & 1];   // layer 2 reuses y0
            double* pl = (l == 2) ? pooled_d : nullptr;
            for (int t0 = 0; t0 < TT; t0 += CH) {
                k_gemm_xg<<<dim3(CH * BB / 128, G3 / 128), 256, 0, stream>>>(
                    src + (size_t)t0 * BB * HH, Wih[l], bih[l], xg);
                k_scan_x<<<256, 512, 0, stream>>>(
                    xg, Whh[l], bhh[l], dst, flags + (binst++) * 512, pl, t0, t0 + CH);
            }
        }
        k_poolfin<<<(BB * HH + 511) / 512, 512, 0, stream>>>(pooled_d, pooled_f);
        k_fc<<<dim3(2, 32), 256, 0, stream>>>(pooled_f, fc1w, fc1b, fc1o, HH, 512, 1);
    } else {
        // fallback (never expected: ws >= 235 MB proven in round 10)
        float* pooled_fb = pooled_f;
        k_scan<8><<<256, 512, 0, stream>>>(x, Wih[0], Whh[0], bih[0], bhh[0], y0,
                                           bars + (binst++) * 128, nullptr);
        k_scan<HH><<<256, 512, 0, stream>>>(y0, Wih[1], Whh[1], bih[1], bhh[1], y1,
                                            bars + (binst++) * 128, nullptr);
        k_scan<HH><<<256, 512, 0, stream>>>(y1, Wih[2], Whh[2], bih[2], bhh[2], y0,
                                            bars + (binst++) * 128, pooled_fb);
        k_fc<<<dim3(2, 32), 256, 0, stream>>>(pooled_fb, fc1w, fc1b, fc1o, HH, 512, 1);
    }

    k_fc<<<dim3(1, 32), 256, 0, stream>>>(fc1o, fc2w, fc2b, fc2o, 512, 256, 1);
    k_fc<<<dim3(1, 32), 256, 0, stream>>>(fc2o, fc3w, fc3b, (float*)d_out, 256, 1, 0);
}

// Round 20
// 16281.262 us; speedup vs baseline: 1.3623x; 1.0655x over previous
//
#include <hip/hip_runtime.h>
#include <cmath>

#define TT 512
#define BB 32
#define HH 1024
#define G3 3072

// ---------------------------------------------------------------------------
// mv_phase (fallback k_scan only): LDS-staged matvec, round-6 structure.
// ---------------------------------------------------------------------------
__device__ __forceinline__ void mv_phase(
    float (*wAll)[HH],              // rows [wrow, wrow+12)
    float* stgL,                    // [32*256]
    float (*part)[12][32],          // [16][12][32]
    const float* __restrict__ src,  // [32][1024] row-major
    int wrow, int tid)
{
    const int wv = tid >> 6, l = tid & 63;
    const int ks = l >> 3, bg = l & 7;
    float acc[12][4];
#pragma unroll
    for (int r = 0; r < 12; r++) {
        acc[r][0] = 0.f; acc[r][1] = 0.f; acc[r][2] = 0.f; acc[r][3] = 0.f;
    }

    float4 ld[4];
#pragma unroll
    for (int i = 0; i < 4; i++)
        ld[i] = *(const float4*)&src[(size_t)(i * 8 + wv) * HH + l * 4];

#pragma unroll
    for (int c = 0; c < 4; c++) {
        __syncthreads();
#pragma unroll
        for (int i = 0; i < 4; i++) {
            int b = i * 8 + wv;
            *(float4*)&stgL[b * 256 + ((l ^ ((b >> 2) & 7)) << 2)] = ld[i];
        }
        __syncthreads();
        if (c < 3) {
#pragma unroll
            for (int i = 0; i < 4; i++)
                ld[i] = *(const float4*)&src[(size_t)(i * 8 + wv) * HH + (c + 1) * 256 + l * 4];
        }
        const int kw = c * 256 + wv * 32 + ks * 4;
        const int kb = wv * 8 + ks;
        float4 h4[4];
#pragma unroll
        for (int e = 0; e < 4; e++) {
            int b = bg * 4 + e;
            h4[e] = *(const float4*)&stgL[b * 256 + ((kb ^ ((b >> 2) & 7)) << 2)];
        }
#pragma unroll
        for (int r = 0; r < 12; r++) {
            float4 w4 = *(const float4*)&wAll[wrow + r][kw];
#pragma unroll
            for (int e = 0; e < 4; e++) {
                acc[r][e] = fmaf(w4.x, h4[e].x, acc[r][e]);
                acc[r][e] = fmaf(w4.y, h4[e].y, acc[r][e]);
                acc[r][e] = fmaf(w4.z, h4[e].z, acc[r][e]);
                acc[r][e] = fmaf(w4.w, h4[e].w, acc[r][e]);
            }
        }
    }
#pragma unroll
    for (int r = 0; r < 12; r++)
#pragma unroll
        for (int e = 0; e < 4; e++) {
            float v = acc[r][e];
            v += __shfl_xor(v, 16, 64);
            v += __shfl_xor(v, 32, 64);
            acc[r][e] = v;
        }
    if (l < 16) {
        int s = l >> 3, bgw = l & 7;
#pragma unroll
        for (int r = 0; r < 12; r++) {
            float4 o = make_float4(acc[r][0], acc[r][1], acc[r][2], acc[r][3]);
            *(float4*)&part[wv * 2 + s][r][bgw * 4] = o;
        }
    }
}

// ---------------------------------------------------------------------------
// Fallback-only scan (ws too small for chunked path). Unchanged.
// ---------------------------------------------------------------------------
template<int IN_DIM>
__global__ __launch_bounds__(512, 2) void k_scan(
    const float* __restrict__ xsrc,
    const float* __restrict__ Wih,
    const float* __restrict__ Whh,
    const float* __restrict__ bih,
    const float* __restrict__ bhh,
    float* __restrict__ y,
    int* __restrict__ barx,
    float* __restrict__ pool)
{
    __shared__ float wAll[24][HH];
    __shared__ float stgL[32 * 256];
    __shared__ float part[16][12][32];
    __shared__ float bi[12], bh[12];
    __shared__ double pool_l[128];

    const int tid = threadIdx.x;
    const int j0 = blockIdx.x * 4;

    for (int i = tid; i < 12 * 256; i += 512) {
        int r = i >> 8, c4 = (i & 255) * 4;
        int g = r >> 2, jj = r & 3;
        *(float4*)&wAll[r][c4] =
            *(const float4*)&Whh[(size_t)(g * HH + j0 + jj) * HH + c4];
    }
    if (IN_DIM == HH) {
        for (int i = tid; i < 12 * 256; i += 512) {
            int r = i >> 8, c4 = (i & 255) * 4;
            int g = r >> 2, jj = r & 3;
            *(float4*)&wAll[12 + r][c4] =
                *(const float4*)&Wih[(size_t)(g * HH + j0 + jj) * HH + c4];
        }
    } else {
        if (tid < 96) {
            int r = tid >> 3, d = tid & 7;
            int g = r >> 2, jj = r & 3;
            wAll[12 + r][d] = Wih[(size_t)(g * HH + j0 + jj) * IN_DIM + d];
        }
    }
    if (tid < 12) {
        int g = tid >> 2, jj = tid & 3;
        bi[tid] = bih[g * HH + j0 + jj];
        bh[tid] = bhh[g * HH + j0 + jj];
    }
    if (tid < 128) pool_l[tid] = 0.0;
    __syncthreads();

    float hp_reg = 0.f;
    for (int t = 0; t < TT; t++) {
        double ig0 = 0.0, ig1 = 0.0, ig2 = 0.0;
        if (IN_DIM == HH) {
            mv_phase(wAll, stgL, part, xsrc + (size_t)t * BB * HH, 12, tid);
            __syncthreads();
            if (tid < 128) {
                int b = tid >> 2, jj = tid & 3;
                ig0 = bi[jj]; ig1 = bi[4 + jj]; ig2 = bi[8 + jj];
#pragma unroll
                for (int p = 0; p < 16; p++) {
                    ig0 += part[p][jj][b];
                    ig1 += part[p][4 + jj][b];
                    ig2 += part[p][8 + jj][b];
                }
            }
        }
        if (t > 0) {
            if (tid < 8) {
                const int target = 32 * t;
                while (__hip_atomic_load(&barx[tid * 16], __ATOMIC_RELAXED,
                                         __HIP_MEMORY_SCOPE_AGENT) < target)
                    __builtin_amdgcn_s_sleep(1);
            }
            __syncthreads();
            mv_phase(wAll, stgL, part, y + (size_t)(t - 1) * BB * HH, 0, tid);
            __syncthreads();
        }
        if (tid < 128) {
            int b = tid >> 2, jj = tid & 3, jg = j0 + jj;
            double hg0 = bh[jj], hg1 = bh[4 + jj], hg2 = bh[8 + jj];
            if (t > 0) {
#pragma unroll
                for (int p = 0; p < 16; p++) {
                    hg0 += part[p][jj][b];
                    hg1 += part[p][4 + jj][b];
                    hg2 += part[p][8 + jj][b];
                }
            }
            if (IN_DIM != HH) {
                const float* xp = xsrc + ((size_t)b * TT + t) * IN_DIM;
                float xv[8];
                *(float4*)&xv[0] = *(const float4*)&xp[0];
                *(float4*)&xv[4] = *(const float4*)&xp[4];
                float s0 = 0.f, s1 = 0.f, s2 = 0.f;
#pragma unroll
                for (int d = 0; d < 8; d++) {
                    s0 = fmaf(wAll[12 + jj][d], xv[d], s0);
                    s1 = fmaf(wAll[16 + jj][d], xv[d], s1);
                    s2 = fmaf(wAll[20 + jj][d], xv[d], s2);
                }
                ig0 = (double)bi[jj] + s0;
                ig1 = (double)bi[4 + jj] + s1;
                ig2 = (double)bi[8 + jj] + s2;
            }
            float rr = 1.f / (1.f + expf(-(float)(ig0 + hg0)));
            float zz = 1.f / (1.f + expf(-(float)(ig1 + hg1)));
            float nn = tanhf((float)(ig2 + (double)rr * hg2));
            float hnew = (1.f - zz) * nn + zz * hp_reg;
            hp_reg = hnew;
            __hip_atomic_store(&y[(size_t)t * BB * HH + b * HH + jg], hnew,
                               __ATOMIC_RELAXED, __HIP_MEMORY_SCOPE_AGENT);
            if (pool != nullptr) pool_l[tid] += (double)hnew;
        }
        if (t < TT - 1) {
            __syncthreads();
            if (tid == 0)
                __hip_atomic_fetch_add(&barx[(blockIdx.x & 7) * 16], 1,
                                       __ATOMIC_RELAXED, __HIP_MEMORY_SCOPE_AGENT);
        }
    }
    __syncthreads();
    if (pool != nullptr && tid < 128) {
        int b = tid >> 2, jj = tid & 3;
        pool[b * HH + j0 + jj] = (float)(pool_l[tid] * (1.0 / 512.0));
    }
}

// ---------------------------------------------------------------------------
// Hidden-only CHUNKED scan — round-16 configuration (session best: 2.49 ms).
// 512 threads, direct global->register h loads (16 float4 in flight),
// single per-block done-flag, trailing block-wide sync before signal.
// r17 (1024thr), r18 (wave0 gate), r19 (2-flag early signal) all regressed;
// this is the measured optimum of the design space.
// ---------------------------------------------------------------------------
__global__ __launch_bounds__(512, 1) void k_scan_x(
    const float* __restrict__ xg,
    const float* __restrict__ Whh,
    const float* __restrict__ bhh,
    float* __restrict__ y,
    int* __restrict__ flagx,          // [256] per-block step flags (zeroed)
    double* __restrict__ pool,
    int t0, int t1)
{
    __shared__ float wAll[12][HH];        // 48 KB
    __shared__ float part[16][12][32];    // 24.6 KB
    __shared__ float bh[12];
    __shared__ double pool_l[128];

    const int tid = threadIdx.x;
    const int j0 = blockIdx.x * 4;
    const int wv = tid >> 6, l = tid & 63;
    const int ks = l >> 3, bg = l & 7;

    for (int i = tid; i < 12 * 256; i += 512) {
        int r = i >> 8, c4 = (i & 255) * 4;
        int g = r >> 2, jj = r & 3;
        *(float4*)&wAll[r][c4] =
            *(const float4*)&Whh[(size_t)(g * HH + j0 + jj) * HH + c4];
    }
    if (tid < 12) bh[tid] = bhh[(tid >> 2) * HH + j0 + (tid & 3)];
    if (tid < 128) pool_l[tid] = 0.0;

    const int gb = tid >> 2, gjj = tid & 3;
    float hp_reg = 0.f;
    if (t0 > 0 && tid < 128)
        hp_reg = y[(size_t)(t0 - 1) * BB * HH + gb * HH + j0 + gjj];
    __syncthreads();

    for (int t = t0; t < t1; t++) {
        // prefetch this step's input gates before the barrier poll
        float xr = 0.f, xz = 0.f, xn = 0.f;
        if (tid < 128) {
            const float* xrow = xg + ((size_t)(t - t0) * BB + gb) * G3;
            xr = xrow[j0 + gjj];
            xz = xrow[HH + j0 + gjj];
            xn = xrow[2 * HH + j0 + gjj];
        }
        if (t > t0) {
            if (tid < 64) {                      // wave 0 polls all 256 flags
                const int target = t - t0;
                const int* fp = flagx + tid * 4;
                for (;;) {
                    int f0 = __hip_atomic_load(fp + 0, __ATOMIC_RELAXED,
                                               __HIP_MEMORY_SCOPE_AGENT);
                    int f1 = __hip_atomic_load(fp + 1, __ATOMIC_RELAXED,
                                               __HIP_MEMORY_SCOPE_AGENT);
                    int f2 = __hip_atomic_load(fp + 2, __ATOMIC_RELAXED,
                                               __HIP_MEMORY_SCOPE_AGENT);
                    int f3 = __hip_atomic_load(fp + 3, __ATOMIC_RELAXED,
                                               __HIP_MEMORY_SCOPE_AGENT);
                    int m01 = f0 < f1 ? f0 : f1;
                    int m23 = f2 < f3 ? f2 : f3;
                    int m = m01 < m23 ? m01 : m23;
                    if (__all(m >= target)) break;
                    __builtin_amdgcn_s_sleep(1);
                }
            }
            __syncthreads();
        }
        if (t > 0) {
            const float* hsrc = y + (size_t)(t - 1) * BB * HH;
            // 16 direct loads, all in flight at once
            float4 hr[4][4];
#pragma unroll
            for (int c = 0; c < 4; c++)
#pragma unroll
                for (int e = 0; e < 4; e++)
                    hr[c][e] = *(const float4*)
                        &hsrc[(size_t)(bg * 4 + e) * HH + c * 256 + wv * 32 + ks * 4];

            float acc[12][4];
#pragma unroll
            for (int r = 0; r < 12; r++) {
                acc[r][0] = 0.f; acc[r][1] = 0.f; acc[r][2] = 0.f; acc[r][3] = 0.f;
            }
#pragma unroll
            for (int c = 0; c < 4; c++) {
                const int kw = c * 256 + wv * 32 + ks * 4;
#pragma unroll
                for (int r = 0; r < 12; r++) {
                    float4 w4 = *(const float4*)&wAll[r][kw];
#pragma unroll
                    for (int e = 0; e < 4; e++) {
                        acc[r][e] = fmaf(w4.x, hr[c][e].x, acc[r][e]);
                        acc[r][e] = fmaf(w4.y, hr[c][e].y, acc[r][e]);
                        acc[r][e] = fmaf(w4.z, hr[c][e].z, acc[r][e]);
                        acc[r][e] = fmaf(w4.w, hr[c][e].w, acc[r][e]);
                    }
                }
            }
#pragma unroll
            for (int r = 0; r < 12; r++)
#pragma unroll
                for (int e = 0; e < 4; e++) {
                    float v = acc[r][e];
                    v += __shfl_xor(v, 16, 64);
                    v += __shfl_xor(v, 32, 64);
                    acc[r][e] = v;
                }
            if (l < 16) {
                int s = l >> 3, bgw = l & 7;
#pragma unroll
                for (int r = 0; r < 12; r++) {
                    float4 o = make_float4(acc[r][0], acc[r][1], acc[r][2], acc[r][3]);
                    *(float4*)&part[wv * 2 + s][r][bgw * 4] = o;
                }
            }
            __syncthreads();
        }
        if (tid < 128) {
            double hg0 = bh[gjj], hg1 = bh[4 + gjj], hg2 = bh[8 + gjj];
            if (t > 0) {
#pragma unroll
                for (int p = 0; p < 16; p++) {
                    hg0 += part[p][gjj][gb];
                    hg1 += part[p][4 + gjj][gb];
                    hg2 += part[p][8 + gjj][gb];
                }
            }
            float rr = 1.f / (1.f + expf(-(xr + (float)hg0)));
            float zz = 1.f / (1.f + expf(-(xz + (float)hg1)));
            float nn = tanhf(xn + rr * (float)hg2);
            float hnew = (1.f - zz) * nn + zz * hp_reg;
            hp_reg = hnew;
            __hip_atomic_store(&y[(size_t)t * BB * HH + gb * HH + j0 + gjj], hnew,
                               __ATOMIC_RELAXED, __HIP_MEMORY_SCOPE_AGENT);
            if (pool != nullptr) pool_l[tid] += (double)hnew;
        }
        if (t < t1 - 1) {
            __syncthreads();   // acks all waves' y[t] stores (vmcnt0 drain)
            if (tid == 0)
                __hip_atomic_store(&flagx[blockIdx.x], t - t0 + 1,
                                   __ATOMIC_RELAXED, __HIP_MEMORY_SCOPE_AGENT);
        }
    }
    __syncthreads();
    if (pool != nullptr && tid < 128)
        pool[gb * HH + j0 + gjj] += pool_l[tid];   // serialized chunk kernels
}

// ---------------------------------------------------------------------------
// pooled_f[i] = pooled_d[i] / 512
// ---------------------------------------------------------------------------
__global__ __launch_bounds__(512) void k_poolfin(const double* __restrict__ pd,
                                                 float* __restrict__ pf)
{
    int i = blockIdx.x * 512 + threadIdx.x;
    if (i < BB * HH) pf[i] = (float)(pd[i] * (1.0 / 512.0));
}

// ---------------------------------------------------------------------------
// xg GEMM (layers 1,2): C[m][n] = sum_k A[m][k]*Bw[n][k] + bias[n]
// 128x128 tile, BK=16, 256 threads, 8x8 microtile.
// ---------------------------------------------------------------------------
__global__ __launch_bounds__(256, 2) void k_gemm_xg(const float* __restrict__ A,
                                                    const float* __restrict__ Bw,
                                                    const float* __restrict__ bias,
                                                    float* __restrict__ C)
{
    __shared__ float As[16][132];
    __shared__ float Bs[16][132];
    const int tid = threadIdx.x;
    const int tx = tid & 15, ty = tid >> 4;
    const int bm = blockIdx.x * 128, bn = blockIdx.y * 128;
    float acc[8][8];
#pragma unroll
    for (int i = 0; i < 8; i++)
#pragma unroll
        for (int j = 0; j < 8; j++) acc[i][j] = 0.f;

    const int srow = tid >> 1, sch = (tid & 1) * 8;
    for (int k0 = 0; k0 < HH; k0 += 16) {
        {
            const float* ap = &A[(size_t)(bm + srow) * HH + k0 + sch];
            float4 v0 = *(const float4*)ap;
            float4 v1 = *(const float4*)(ap + 4);
            As[sch + 0][srow] = v0.x; As[sch + 1][srow] = v0.y;
            As[sch + 2][srow] = v0.z; As[sch + 3][srow] = v0.w;
            As[sch + 4][srow] = v1.x; As[sch + 5][srow] = v1.y;
            As[sch + 6][srow] = v1.z; As[sch + 7][srow] = v1.w;
            const float* bp = &Bw[(size_t)(bn + srow) * HH + k0 + sch];
            float4 u0 = *(const float4*)bp;
            float4 u1 = *(const float4*)(bp + 4);
            Bs[sch + 0][srow] = u0.x; Bs[sch + 1][srow] = u0.y;
            Bs[sch + 2][srow] = u0.z; Bs[sch + 3][srow] = u0.w;
            Bs[sch + 4][srow] = u1.x; Bs[sch + 5][srow] = u1.y;
            Bs[sch + 6][srow] = u1.z; Bs[sch + 7][srow] = u1.w;
        }
        __syncthreads();
#pragma unroll
        for (int k = 0; k < 16; k++) {
            float a[8], b[8];
            *(float4*)&a[0] = *(const float4*)&As[k][ty * 8];
            *(float4*)&a[4] = *(const float4*)&As[k][ty * 8 + 4];
            *(float4*)&b[0] = *(const float4*)&Bs[k][tx * 8];
            *(float4*)&b[4] = *(const float4*)&Bs[k][tx * 8 + 4];
#pragma unroll
            for (int i = 0; i < 8; i++)
#pragma unroll
                for (int j = 0; j < 8; j++)
                    acc[i][j] = fmaf(a[i], b[j], acc[i][j]);
        }
        __syncthreads();
    }
#pragma unroll
    for (int i = 0; i < 8; i++) {
        float o[8];
#pragma unroll
        for (int j = 0; j < 8; j++) o[j] = acc[i][j] + bias[bn + tx * 8 + j];
        float* cp = &C[(size_t)(bm + ty * 8 + i) * G3 + bn + tx * 8];
        *(float4*)cp = *(float4*)&o[0];
        *(float4*)(cp + 4) = *(float4*)&o[4];
    }
}

// ---------------------------------------------------------------------------
// xg GEMM for layer 0 (K=8): C[m][n] = sum_{k<8} x[b][t][k]*W[n][k] + bias[n]
// m local to chunk: m = (t-t0)*32 + b. Grid (CH*32/128, 24), 256 threads.
// ---------------------------------------------------------------------------
__global__ __launch_bounds__(256) void k_gemm_xg0(const float* __restrict__ x,
                                                  const float* __restrict__ W,
                                                  const float* __restrict__ bias,
                                                  float* __restrict__ C,
                                                  int t0)
{
    __shared__ float As[128][8];
    __shared__ float Bs[128][8];
    const int tid = threadIdx.x;
    const int bm = blockIdx.x * 128, bn = blockIdx.y * 128;
    {
        int r = tid >> 1, hf = (tid & 1) * 4;
        int m = bm + r;                       // chunk-local row
        int b = m & 31, tt = t0 + (m >> 5);
        *(float4*)&As[r][hf] = *(const float4*)&x[((size_t)b * TT + tt) * 8 + hf];
        *(float4*)&Bs[r][hf] = *(const float4*)&W[(size_t)(bn + r) * 8 + hf];
    }
    __syncthreads();
    const int tx = tid & 15, ty = tid >> 4;
    float acc[8][8];
#pragma unroll
    for (int i = 0; i < 8; i++)
#pragma unroll
        for (int j = 0; j < 8; j++) acc[i][j] = 0.f;
#pragma unroll
    for (int k = 0; k < 8; k++) {
        float a[8], b[8];
#pragma unroll
        for (int i = 0; i < 8; i++) a[i] = As[ty * 8 + i][k];
#pragma unroll
        for (int j = 0; j < 8; j++) b[j] = Bs[tx * 8 + j][k];
#pragma unroll
        for (int i = 0; i < 8; i++)
#pragma unroll
            for (int j = 0; j < 8; j++)
                acc[i][j] = fmaf(a[i], b[j], acc[i][j]);
    }
#pragma unroll
    for (int i = 0; i < 8; i++) {
        float o[8];
#pragma unroll
        for (int j = 0; j < 8; j++) o[j] = acc[i][j] + bias[bn + tx * 8 + j];
        float* cp = &C[(size_t)(bm + ty * 8 + i) * G3 + bn + tx * 8];
        *(float4*)cp = *(float4*)&o[0];
        *(float4*)(cp + 4) = *(float4*)&o[4];
    }
}

// ---------------------------------------------------------------------------
__global__ __launch_bounds__(256) void k_fc(const float* __restrict__ in,
                                            const float* __restrict__ w,
                                            const float* __restrict__ bias,
                                            float* __restrict__ out,
                                            int ind, int outd, int dorelu)
{
    int b = blockIdx.y;
    int o = blockIdx.x * 256 + threadIdx.x;
    if (o >= outd) return;
    const float* ip = in + (size_t)b * ind;
    const float* wp = w + (size_t)o * ind;
    double s = (double)bias[o];
    for (int k = 0; k < ind; k += 4) {
        float4 wv = *(const float4*)&wp[k];
        float4 iv = *(const float4*)&ip[k];
        s += (double)iv.x * wv.x + (double)iv.y * wv.y
           + (double)iv.z * wv.z + (double)iv.w * wv.w;
    }
    float v = (float)s;
    if (dorelu) v = fmaxf(v, 0.f);
    out[(size_t)b * outd + o] = v;
}

// ---------------------------------------------------------------------------
extern "C" void kernel_launch(void* const* d_in, const int* in_sizes, int n_in,
                              void* d_out, int out_size, void* d_ws, size_t ws_size,
                              hipStream_t stream)
{
    (void)in_sizes; (void)n_in; (void)out_size;
    const float* x    = (const float*)d_in[0];
    const float* Wih[3] = {(const float*)d_in[1], (const float*)d_in[5], (const float*)d_in[9]};
    const float* Whh[3] = {(const float*)d_in[2], (const float*)d_in[6], (const float*)d_in[10]};
    const float* bih[3] = {(const float*)d_in[3], (const float*)d_in[7], (const float*)d_in[11]};
    const float* bhh[3] = {(const float*)d_in[4], (const float*)d_in[8], (const float*)d_in[12]};
    const float* fc1w = (const float*)d_in[13];
    const float* fc1b = (const float*)d_in[14];
    const float* fc2w = (const float*)d_in[15];
    const float* fc2b = (const float*)d_in[16];
    const float* fc3w = (const float*)d_in[17];
    const float* fc3b = (const float*)d_in[18];

    // workspace layout
    int*    bars     = (int*)d_ws;                 // 96 x 128 ints (fallback)
    int*    flags    = bars + 96 * 128;            // 96 x 256 ints (scan_x)
    double* pooled_d = (double*)(flags + 96 * 256);   // 256 KB
    float*  pooled_f = (float*)(pooled_d + BB * HH);  // 128 KB
    float*  fc1o     = pooled_f + BB * HH;
    float*  fc2o     = fc1o + BB * 512;
    float*  y0       = fc2o + BB * 256;               // 67.1 MB
    float*  y1       = y0 + (size_t)TT * BB * HH;     // 67.1 MB
    float*  xg       = y1 + (size_t)TT * BB * HH;     // CH*393 KB

    const size_t base = (size_t)((char*)xg - (char*)d_ws);
    if (ws_size < base) return;

    int CH = 0;
    for (int c = 512; c >= 16; c >>= 1) {
        if (base + (size_t)c * BB * G3 * 4 <= ws_size) { CH = c; break; }
    }

    hipMemsetAsync(bars, 0, (96 * 128 + 96 * 256) * sizeof(int), stream);
    hipMemsetAsync(pooled_d, 0, BB * HH * sizeof(double), stream);

    int binst = 0;
    if (CH > 0) {
        // layer 0: K=8 gemm + hidden-only scan (same structure as layers 1,2)
        for (int t0 = 0; t0 < TT; t0 += CH) {
            k_gemm_xg0<<<dim3(CH * BB / 128, G3 / 128), 256, 0, stream>>>(
                x, Wih[0], bih[0], xg, t0);
            k_scan_x<<<256, 512, 0, stream>>>(
                xg, Whh[0], bhh[0], y0, flags + (binst++) * 256, nullptr, t0, t0 + CH);
        }
        float* ybuf[2] = {y0, y1};
        for (int l = 1; l <= 2; l++) {
            const float* src = ybuf[(l - 1) & 1];
            float* dst = ybuf[l & 1];   // layer 2 reuses y0
            double* pl = (l == 2) ? pooled_d : nullptr;
            for (int t0 = 0; t0 < TT; t0 += CH) {
                k_gemm_xg<<<dim3(CH * BB / 128, G3 / 128), 256, 0, stream>>>(
                    src + (size_t)t0 * BB * HH, Wih[l], bih[l], xg);
                k_scan_x<<<256, 512, 0, stream>>>(
                    xg, Whh[l], bhh[l], dst, flags + (binst++) * 256, pl, t0, t0 + CH);
            }
        }
        k_poolfin<<<(BB * HH + 511) / 512, 512, 0, stream>>>(pooled_d, pooled_f);
        k_fc<<<dim3(2, 32), 256, 0, stream>>>(pooled_f, fc1w, fc1b, fc1o, HH, 512, 1);
    } else {
        // fallback (never expected: ws >= 235 MB proven in round 10)
        float* pooled_fb = pooled_f;
        k_scan<8><<<256, 512, 0, stream>>>(x, Wih[0], Whh[0], bih[0], bhh[0], y0,
                                           bars + (binst++) * 128, nullptr);
        k_scan<HH><<<256, 512, 0, stream>>>(y0, Wih[1], Whh[1], bih[1], bhh[1], y1,
                                            bars + (binst++) * 128, nullptr);
        k_scan<HH><<<256, 512, 0, stream>>>(y1, Wih[2], Whh[2], bih[2], bhh[2], y0,
                                            bars + (binst++) * 128, pooled_fb);
        k_fc<<<dim3(2, 32), 256, 0, stream>>>(pooled_fb, fc1w, fc1b, fc1o, HH, 512, 1);
    }

    k_fc<<<dim3(1, 32), 256, 0, stream>>>(fc1o, fc2w, fc2b, fc2o, 512, 256, 1);
    k_fc<<<dim3(1, 32), 256, 0, stream>>>(fc2o, fc3w, fc3b, (float*)d_out, 256, 1, 0);
}